// Round 1
// baseline (1669.616 us; speedup 1.0000x reference)
//
#include <hip/hip_runtime.h>

// ---------------------------------------------------------------------------
// SupervisedGATEncoder: 2-layer GAT (4 heads x 64 -> BN -> ReLU -> 1 head x 32)
// + graph-mean prediction head. fp32 throughout.
//
// Inputs (setup_inputs order):
//  0 x[N,128] 1 edge_index[2,E](int32) 2 W0[128,256] 3 a_src0[4,64] 4 a_dst0[4,64]
//  5 b0[256]  6 bn_gamma[256] 7 bn_beta[256] 8 bn_mean[256] 9 bn_var[256]
// 10 W1[256,32] 11 a_src1[32] 12 a_dst1[32] 13 b1[32]
// 14 head_W1[32,64] 15 head_b1[64] 16 head_W2[64] 17 head_b2[1]
// Output: node_embeddings[N*32] ++ predictions[1]
// ---------------------------------------------------------------------------

#define NEG_SLOPE 0.2f
#define BN_EPS 1e-5f

__device__ __forceinline__ unsigned f2ord(float f) {
  unsigned b = __float_as_uint(f);
  return (b & 0x80000000u) ? ~b : (b | 0x80000000u);
}
__device__ __forceinline__ float ord2f(unsigned u) {
  return (u & 0x80000000u) ? __uint_as_float(u & 0x7fffffffu)
                           : __uint_as_float(~u);
}

// ---------------- GEMM0: C[M,256] = A[M,128] @ B[128,256] ------------------
// tile 64 rows x 64 cols, K chunked by 64; thread computes 4x4.
__global__ __launch_bounds__(256) void gemm0_kernel(
    const float* __restrict__ A, const float* __restrict__ B,
    float* __restrict__ C, int M) {
  __shared__ float As[64][68];   // +4 pad: 16B-aligned rows, 2-way banks max
  __shared__ float Bs[64][64];
  const int t = threadIdx.x;
  const int row0 = blockIdx.x * 64;
  const int col0 = blockIdx.y * 64;
  const int tr = t >> 4;   // 0..15 -> rows tr*4..tr*4+3
  const int tc = t & 15;   // 0..15 -> cols tc*4..tc*4+3
  float acc[4][4] = {};
  for (int k0 = 0; k0 < 128; k0 += 64) {
    __syncthreads();
    // load A chunk 64x64 (scalar, coalesced along k)
    #pragma unroll
    for (int i = 0; i < 16; ++i) {
      int idx = t + i * 256;
      int r = idx >> 6, k = idx & 63;
      int gr = row0 + r;
      As[r][k] = (gr < M) ? A[(size_t)gr * 128 + k0 + k] : 0.f;
    }
    // load B chunk 64x64 (float4, coalesced)
    #pragma unroll
    for (int i = 0; i < 4; ++i) {
      int idx = t + i * 256;          // float4 slot: 64 rows x 16
      int k = idx >> 4, c4 = idx & 15;
      *reinterpret_cast<float4*>(&Bs[k][c4 * 4]) =
          *reinterpret_cast<const float4*>(&B[(size_t)(k0 + k) * 256 + col0 + c4 * 4]);
    }
    __syncthreads();
    #pragma unroll
    for (int k = 0; k < 64; k += 4) {
      float4 a[4], b[4];
      #pragma unroll
      for (int i = 0; i < 4; ++i)
        a[i] = *reinterpret_cast<const float4*>(&As[tr * 4 + i][k]);
      #pragma unroll
      for (int j = 0; j < 4; ++j)
        b[j] = *reinterpret_cast<const float4*>(&Bs[k + j][tc * 4]);
      #pragma unroll
      for (int i = 0; i < 4; ++i) {
        acc[i][0] += a[i].x * b[0].x + a[i].y * b[1].x + a[i].z * b[2].x + a[i].w * b[3].x;
        acc[i][1] += a[i].x * b[0].y + a[i].y * b[1].y + a[i].z * b[2].y + a[i].w * b[3].y;
        acc[i][2] += a[i].x * b[0].z + a[i].y * b[1].z + a[i].z * b[2].z + a[i].w * b[3].z;
        acc[i][3] += a[i].x * b[0].w + a[i].y * b[1].w + a[i].z * b[2].w + a[i].w * b[3].w;
      }
    }
  }
  #pragma unroll
  for (int i = 0; i < 4; ++i) {
    int gr = row0 + tr * 4 + i;
    if (gr < M) {
      float4 o = make_float4(acc[i][0], acc[i][1], acc[i][2], acc[i][3]);
      *reinterpret_cast<float4*>(&C[(size_t)gr * 256 + col0 + tc * 4]) = o;
    }
  }
}

// ---------------- GEMM1: C[M,32] = A[M,256] @ B[256,32] --------------------
// tile 128 rows x 32 cols, K chunked by 64; thread computes 4x4.
__global__ __launch_bounds__(256) void gemm1_kernel(
    const float* __restrict__ A, const float* __restrict__ B,
    float* __restrict__ C, int M) {
  __shared__ float As[128][68];
  __shared__ float Bs[64][32];
  const int t = threadIdx.x;
  const int row0 = blockIdx.x * 128;
  const int tr = t >> 3;  // 0..31 -> rows tr*4..
  const int tc = t & 7;   // 0..7  -> cols tc*4..
  float acc[4][4] = {};
  for (int k0 = 0; k0 < 256; k0 += 64) {
    __syncthreads();
    #pragma unroll
    for (int i = 0; i < 32; ++i) {
      int idx = t + i * 256;
      int r = idx >> 6, k = idx & 63;
      int gr = row0 + r;
      As[r][k] = (gr < M) ? A[(size_t)gr * 256 + k0 + k] : 0.f;
    }
    #pragma unroll
    for (int i = 0; i < 2; ++i) {
      int idx = t + i * 256;          // float4 slots: 64 x 8
      int k = idx >> 3, c4 = idx & 7;
      *reinterpret_cast<float4*>(&Bs[k][c4 * 4]) =
          *reinterpret_cast<const float4*>(&B[(size_t)(k0 + k) * 32 + c4 * 4]);
    }
    __syncthreads();
    #pragma unroll
    for (int k = 0; k < 64; k += 4) {
      float4 a[4], b[4];
      #pragma unroll
      for (int i = 0; i < 4; ++i)
        a[i] = *reinterpret_cast<const float4*>(&As[tr * 4 + i][k]);
      #pragma unroll
      for (int j = 0; j < 4; ++j)
        b[j] = *reinterpret_cast<const float4*>(&Bs[k + j][tc * 4]);
      #pragma unroll
      for (int i = 0; i < 4; ++i) {
        acc[i][0] += a[i].x * b[0].x + a[i].y * b[1].x + a[i].z * b[2].x + a[i].w * b[3].x;
        acc[i][1] += a[i].x * b[0].y + a[i].y * b[1].y + a[i].z * b[2].y + a[i].w * b[3].y;
        acc[i][2] += a[i].x * b[0].z + a[i].y * b[1].z + a[i].z * b[2].z + a[i].w * b[3].z;
        acc[i][3] += a[i].x * b[0].w + a[i].y * b[1].w + a[i].z * b[2].w + a[i].w * b[3].w;
      }
    }
  }
  #pragma unroll
  for (int i = 0; i < 4; ++i) {
    int gr = row0 + tr * 4 + i;
    if (gr < M) {
      float4 o = make_float4(acc[i][0], acc[i][1], acc[i][2], acc[i][3]);
      *reinterpret_cast<float4*>(&C[(size_t)gr * 32 + tc * 4]) = o;
    }
  }
}

// ------------- alpha0: per-node per-head dot(h0 row, a_src/a_dst) ----------
__global__ __launch_bounds__(256) void alpha0_kernel(
    const float* __restrict__ h0, const float* __restrict__ a_src,
    const float* __restrict__ a_dst, float* __restrict__ as_out,
    float* __restrict__ ad_out, int N) {
  const int lane = threadIdx.x & 63;
  const int wid = threadIdx.x >> 6;
  const int n = blockIdx.x * 4 + wid;
  if (n >= N) return;
  float4 v  = *reinterpret_cast<const float4*>(&h0[(size_t)n * 256 + lane * 4]);
  float4 s4 = *reinterpret_cast<const float4*>(&a_src[lane * 4]);
  float4 d4 = *reinterpret_cast<const float4*>(&a_dst[lane * 4]);
  float ps = v.x * s4.x + v.y * s4.y + v.z * s4.z + v.w * s4.w;
  float pd = v.x * d4.x + v.y * d4.y + v.z * d4.z + v.w * d4.w;
  #pragma unroll
  for (int off = 1; off < 16; off <<= 1) {
    ps += __shfl_xor(ps, off);
    pd += __shfl_xor(pd, off);
  }
  if ((lane & 15) == 0) {
    as_out[n * 4 + (lane >> 4)] = ps;
    ad_out[n * 4 + (lane >> 4)] = pd;
  }
}

// ------------- alpha1: per-node dot(h1 row[32], a_src1/a_dst1) -------------
__global__ __launch_bounds__(256) void alpha1_kernel(
    const float* __restrict__ h1, const float* __restrict__ a_src,
    const float* __restrict__ a_dst, float* __restrict__ as_out,
    float* __restrict__ ad_out, int N) {
  const int lane = threadIdx.x & 63;
  const int wid = threadIdx.x >> 6;
  const int n = blockIdx.x * 8 + wid * 2 + (lane >> 5);
  const int c = lane & 31;
  float ps = 0.f, pd = 0.f;
  if (n < N) {
    float v = h1[(size_t)n * 32 + c];
    ps = v * a_src[c];
    pd = v * a_dst[c];
  }
  #pragma unroll
  for (int off = 1; off < 32; off <<= 1) {
    ps += __shfl_xor(ps, off);
    pd += __shfl_xor(pd, off);
  }
  if (n < N && c == 0) { as_out[n] = ps; ad_out[n] = pd; }
}

// ------------- edge pass A (layer0): leaky score + atomic max --------------
__global__ __launch_bounds__(256) void edge_a0(
    const int* __restrict__ srcs, const int* __restrict__ dsts,
    const float* __restrict__ as, const float* __restrict__ ad,
    float* __restrict__ ew, unsigned* __restrict__ mmax, int E, int N) {
  int e = blockIdx.x * 256 + threadIdx.x;
  if (e >= E + N) return;
  int s, d;
  if (e < E) { s = srcs[e]; d = dsts[e]; } else { s = d = e - E; }
  float4 es = *reinterpret_cast<const float4*>(&as[s * 4]);
  float4 ed = *reinterpret_cast<const float4*>(&ad[d * 4]);
  float v[4] = {es.x + ed.x, es.y + ed.y, es.z + ed.z, es.w + ed.w};
  float o[4];
  #pragma unroll
  for (int h = 0; h < 4; ++h) {
    float x = v[h];
    x = x > 0.f ? x : NEG_SLOPE * x;
    o[h] = x;
    atomicMax(&mmax[d * 4 + h], f2ord(x));
  }
  *reinterpret_cast<float4*>(&ew[(size_t)e * 4]) = make_float4(o[0], o[1], o[2], o[3]);
}

// ------------- edge pass B (layer0): exp + denom -------------------------
__global__ __launch_bounds__(256) void edge_b0(
    const int* __restrict__ dsts, float* __restrict__ ew,
    const unsigned* __restrict__ mmax, float* __restrict__ den, int E, int N) {
  int e = blockIdx.x * 256 + threadIdx.x;
  if (e >= E + N) return;
  int d = (e < E) ? dsts[e] : e - E;
  float4 x4 = *reinterpret_cast<const float4*>(&ew[(size_t)e * 4]);
  float x[4] = {x4.x, x4.y, x4.z, x4.w};
  float w[4];
  #pragma unroll
  for (int h = 0; h < 4; ++h) {
    w[h] = __expf(x[h] - ord2f(mmax[d * 4 + h]));
    atomicAdd(&den[d * 4 + h], w[h]);
  }
  *reinterpret_cast<float4*>(&ew[(size_t)e * 4]) = make_float4(w[0], w[1], w[2], w[3]);
}

// ------------- reciprocal (denom -> 1/denom), generic ---------------------
__global__ __launch_bounds__(256) void recip_kernel(float* __restrict__ p, int n) {
  int i = blockIdx.x * 256 + threadIdx.x;
  if (i < n) p[i] = 1.0f / p[i];
}

// ------------- edge pass C (layer0): scatter-aggregate ---------------------
// one block per edge, thread t handles feature t (head = t/64)
__global__ __launch_bounds__(256) void edge_c0(
    const int* __restrict__ srcs, const int* __restrict__ dsts,
    const float* __restrict__ h0, const float* __restrict__ ew,
    const float* __restrict__ invden, float* __restrict__ agg, int E, int N) {
  int e = blockIdx.x;
  int t = threadIdx.x;
  int s, d;
  if (e < E) { s = srcs[e]; d = dsts[e]; } else { s = d = e - E; }
  int h = t >> 6;
  float alpha = ew[(size_t)e * 4 + h] * invden[d * 4 + h];
  float val = h0[(size_t)s * 256 + t] * alpha;
  atomicAdd(&agg[(size_t)d * 256 + t], val);
}

// ------------- BN(eval) + bias + ReLU, in place ---------------------------
__global__ __launch_bounds__(256) void bn_relu_kernel(
    float* __restrict__ agg, const float* __restrict__ b0,
    const float* __restrict__ gamma, const float* __restrict__ beta,
    const float* __restrict__ mean, const float* __restrict__ var,
    size_t total) {
  size_t i = (size_t)blockIdx.x * 256 + threadIdx.x;
  if (i >= total) return;
  int j = (int)(i & 255);
  float v = agg[i] + b0[j];
  float sc = gamma[j] * rsqrtf(var[j] + BN_EPS);
  v = (v - mean[j]) * sc + beta[j];
  agg[i] = v > 0.f ? v : 0.f;
}

// ------------- layer1 edge passes -----------------------------------------
__global__ __launch_bounds__(256) void edge_a1(
    const int* __restrict__ srcs, const int* __restrict__ dsts,
    const float* __restrict__ as, const float* __restrict__ ad,
    float* __restrict__ ew, unsigned* __restrict__ mmax, int E, int N) {
  int e = blockIdx.x * 256 + threadIdx.x;
  if (e >= E + N) return;
  int s, d;
  if (e < E) { s = srcs[e]; d = dsts[e]; } else { s = d = e - E; }
  float x = as[s] + ad[d];
  x = x > 0.f ? x : NEG_SLOPE * x;
  ew[e] = x;
  atomicMax(&mmax[d], f2ord(x));
}

__global__ __launch_bounds__(256) void edge_b1(
    const int* __restrict__ dsts, float* __restrict__ ew,
    const unsigned* __restrict__ mmax, float* __restrict__ den, int E, int N) {
  int e = blockIdx.x * 256 + threadIdx.x;
  if (e >= E + N) return;
  int d = (e < E) ? dsts[e] : e - E;
  float w = __expf(ew[e] - ord2f(mmax[d]));
  ew[e] = w;
  atomicAdd(&den[d], w);
}

__global__ __launch_bounds__(256) void edge_c1(
    const int* __restrict__ srcs, const int* __restrict__ dsts,
    const float* __restrict__ h1, const float* __restrict__ ew,
    const float* __restrict__ invden, float* __restrict__ agg, int E, int N) {
  size_t idx = (size_t)blockIdx.x * 256 + threadIdx.x;
  size_t Etot = (size_t)E + N;
  size_t e = idx >> 5;
  if (e >= Etot) return;
  int c = (int)(idx & 31);
  int s, d;
  if (e < (size_t)E) { s = srcs[e]; d = dsts[e]; } else { s = d = (int)(e - E); }
  float alpha = ew[e] * invden[d];
  atomicAdd(&agg[(size_t)d * 32 + c], h1[(size_t)s * 32 + c] * alpha);
}

// ------------- final embeddings + graph-sum partials -----------------------
__global__ __launch_bounds__(256) void emb_kernel(
    const float* __restrict__ agg1, const float* __restrict__ b1,
    float* __restrict__ out, float* __restrict__ gsum, int N) {
  __shared__ float red[8][32];
  int t = threadIdx.x;
  int r = blockIdx.x * 8 + (t >> 5);
  int c = t & 31;
  float val = 0.f;
  if (r < N) {
    val = agg1[(size_t)r * 32 + c] + b1[c];
    out[(size_t)r * 32 + c] = val;
  }
  red[t >> 5][c] = val;
  __syncthreads();
  if (t < 32) {
    float s = 0.f;
    #pragma unroll
    for (int i = 0; i < 8; ++i) s += red[i][t];
    atomicAdd(&gsum[t], s);
  }
}

// ------------- prediction head (1 block, 64 threads) -----------------------
__global__ void pred_kernel(
    const float* __restrict__ gsum, const float* __restrict__ hW1,
    const float* __restrict__ hb1, const float* __restrict__ hW2,
    const float* __restrict__ hb2, float* __restrict__ out, int N) {
  int j = threadIdx.x;  // 0..63
  float invN = 1.0f / (float)N;
  float acc = hb1[j];
  #pragma unroll
  for (int c = 0; c < 32; ++c) acc += (gsum[c] * invN) * hW1[c * 64 + j];
  acc = fmaxf(acc, 0.f);
  float v = acc * hW2[j];
  #pragma unroll
  for (int off = 1; off < 64; off <<= 1) v += __shfl_xor(v, off);
  if (j == 0) out[(size_t)N * 32] = v + hb2[0];
}

// ---------------------------------------------------------------------------
extern "C" void kernel_launch(void* const* d_in, const int* in_sizes, int n_in,
                              void* d_out, int out_size, void* d_ws, size_t ws_size,
                              hipStream_t stream) {
  const float* x       = (const float*)d_in[0];
  const int*   ei      = (const int*)d_in[1];
  const float* W0      = (const float*)d_in[2];
  const float* a_src0  = (const float*)d_in[3];
  const float* a_dst0  = (const float*)d_in[4];
  const float* b0      = (const float*)d_in[5];
  const float* bn_g    = (const float*)d_in[6];
  const float* bn_b    = (const float*)d_in[7];
  const float* bn_m    = (const float*)d_in[8];
  const float* bn_v    = (const float*)d_in[9];
  const float* W1      = (const float*)d_in[10];
  const float* a_src1  = (const float*)d_in[11];
  const float* a_dst1  = (const float*)d_in[12];
  const float* b1      = (const float*)d_in[13];
  const float* hW1     = (const float*)d_in[14];
  const float* hb1     = (const float*)d_in[15];
  const float* hW2     = (const float*)d_in[16];
  const float* hb2     = (const float*)d_in[17];

  const int N = in_sizes[0] / 128;
  const int E = in_sizes[1] / 2;
  const int Etot = E + N;
  const int* srcs = ei;
  const int* dsts = ei + E;

  float* out = (float*)d_out;

  // workspace layout (floats)
  float* ws = (float*)d_ws;
  size_t off = 0;
  float* h0   = ws + off; off += (size_t)N * 256;
  float* ew   = ws + off; off += (size_t)Etot * 4;   // layer1 reuses first Etot
  float* as0  = ws + off; off += (size_t)N * 4;
  float* ad0  = ws + off; off += (size_t)N * 4;
  float* as1  = ws + off; off += (size_t)N;
  float* ad1  = ws + off; off += (size_t)N;
  float* h1   = ws + off; off += (size_t)N * 32;
  // --- zeroed region (contiguous) ---
  size_t zoff = off;
  float* agg0 = ws + off; off += (size_t)N * 256;
  float* agg1 = ws + off; off += (size_t)N * 32;
  unsigned* m0 = (unsigned*)(ws + off); off += (size_t)N * 4;
  float* den0 = ws + off; off += (size_t)N * 4;
  unsigned* m1 = (unsigned*)(ws + off); off += (size_t)N;
  float* den1 = ws + off; off += (size_t)N;
  float* gsum = ws + off; off += 32;

  hipMemsetAsync(ws + zoff, 0, (off - zoff) * sizeof(float), stream);

  auto cdiv = [](long a, long b) { return (int)((a + b - 1) / b); };

  // layer 0
  gemm0_kernel<<<dim3(cdiv(N, 64), 4), 256, 0, stream>>>(x, W0, h0, N);
  alpha0_kernel<<<cdiv(N, 4), 256, 0, stream>>>(h0, a_src0, a_dst0, as0, ad0, N);
  edge_a0<<<cdiv(Etot, 256), 256, 0, stream>>>(srcs, dsts, as0, ad0, ew, m0, E, N);
  edge_b0<<<cdiv(Etot, 256), 256, 0, stream>>>(dsts, ew, m0, den0, E, N);
  recip_kernel<<<cdiv((long)N * 4, 256), 256, 0, stream>>>(den0, N * 4);
  edge_c0<<<Etot, 256, 0, stream>>>(srcs, dsts, h0, ew, den0, agg0, E, N);
  bn_relu_kernel<<<cdiv((long)N * 256, 256), 256, 0, stream>>>(
      agg0, b0, bn_g, bn_b, bn_m, bn_v, (size_t)N * 256);

  // layer 1
  gemm1_kernel<<<cdiv(N, 128), 256, 0, stream>>>(agg0, W1, h1, N);
  alpha1_kernel<<<cdiv(N, 8), 256, 0, stream>>>(h1, a_src1, a_dst1, as1, ad1, N);
  edge_a1<<<cdiv(Etot, 256), 256, 0, stream>>>(srcs, dsts, as1, ad1, ew, m1, E, N);
  edge_b1<<<cdiv(Etot, 256), 256, 0, stream>>>(dsts, ew, m1, den1, E, N);
  recip_kernel<<<cdiv(N, 256), 256, 0, stream>>>(den1, N);
  edge_c1<<<cdiv((long)Etot * 32, 256), 256, 0, stream>>>(srcs, dsts, h1, ew, den1, agg1, E, N);

  // output + head
  emb_kernel<<<cdiv(N, 8), 256, 0, stream>>>(agg1, b1, out, gsum, N);
  pred_kernel<<<1, 64, 0, stream>>>(gsum, hW1, hb1, hW2, hb2, out, N);
}

// Round 2
// 793.918 us; speedup vs baseline: 2.1030x; 2.1030x over previous
//
#include <hip/hip_runtime.h>

// ---------------------------------------------------------------------------
// SupervisedGATEncoder: 2-layer GAT (4 heads x 64 -> BN -> ReLU -> 1 head x 32)
// + graph-mean prediction head. fp32 throughout.
//
// R2: CSR-by-dst build + per-node gather aggregation (one wave per node).
// Softmax max/denom are wave-local (no atomics); BN/bias/ReLU fused into
// aggregate epilogues. Eliminates all edge-scatter atomics of R1.
// ---------------------------------------------------------------------------

#define NEG_SLOPE 0.2f
#define BN_EPS 1e-5f

// ---------------- GEMM0: C[M,256] = A[M,128] @ B[128,256] ------------------
__global__ __launch_bounds__(256) void gemm0_kernel(
    const float* __restrict__ A, const float* __restrict__ B,
    float* __restrict__ C, int M) {
  __shared__ float As[64][68];
  __shared__ float Bs[64][64];
  const int t = threadIdx.x;
  const int row0 = blockIdx.x * 64;
  const int col0 = blockIdx.y * 64;
  const int tr = t >> 4;
  const int tc = t & 15;
  float acc[4][4] = {};
  for (int k0 = 0; k0 < 128; k0 += 64) {
    __syncthreads();
    #pragma unroll
    for (int i = 0; i < 16; ++i) {
      int idx = t + i * 256;
      int r = idx >> 6, k = idx & 63;
      int gr = row0 + r;
      As[r][k] = (gr < M) ? A[(size_t)gr * 128 + k0 + k] : 0.f;
    }
    #pragma unroll
    for (int i = 0; i < 4; ++i) {
      int idx = t + i * 256;
      int k = idx >> 4, c4 = idx & 15;
      *reinterpret_cast<float4*>(&Bs[k][c4 * 4]) =
          *reinterpret_cast<const float4*>(&B[(size_t)(k0 + k) * 256 + col0 + c4 * 4]);
    }
    __syncthreads();
    #pragma unroll
    for (int k = 0; k < 64; k += 4) {
      float4 a[4], b[4];
      #pragma unroll
      for (int i = 0; i < 4; ++i)
        a[i] = *reinterpret_cast<const float4*>(&As[tr * 4 + i][k]);
      #pragma unroll
      for (int j = 0; j < 4; ++j)
        b[j] = *reinterpret_cast<const float4*>(&Bs[k + j][tc * 4]);
      #pragma unroll
      for (int i = 0; i < 4; ++i) {
        acc[i][0] += a[i].x * b[0].x + a[i].y * b[1].x + a[i].z * b[2].x + a[i].w * b[3].x;
        acc[i][1] += a[i].x * b[0].y + a[i].y * b[1].y + a[i].z * b[2].y + a[i].w * b[3].y;
        acc[i][2] += a[i].x * b[0].z + a[i].y * b[1].z + a[i].z * b[2].z + a[i].w * b[3].z;
        acc[i][3] += a[i].x * b[0].w + a[i].y * b[1].w + a[i].z * b[2].w + a[i].w * b[3].w;
      }
    }
  }
  #pragma unroll
  for (int i = 0; i < 4; ++i) {
    int gr = row0 + tr * 4 + i;
    if (gr < M) {
      float4 o = make_float4(acc[i][0], acc[i][1], acc[i][2], acc[i][3]);
      *reinterpret_cast<float4*>(&C[(size_t)gr * 256 + col0 + tc * 4]) = o;
    }
  }
}

// ---------------- GEMM1: C[M,32] = A[M,256] @ B[256,32] --------------------
__global__ __launch_bounds__(256) void gemm1_kernel(
    const float* __restrict__ A, const float* __restrict__ B,
    float* __restrict__ C, int M) {
  __shared__ float As[128][68];
  __shared__ float Bs[64][32];
  const int t = threadIdx.x;
  const int row0 = blockIdx.x * 128;
  const int tr = t >> 3;
  const int tc = t & 7;
  float acc[4][4] = {};
  for (int k0 = 0; k0 < 256; k0 += 64) {
    __syncthreads();
    #pragma unroll
    for (int i = 0; i < 32; ++i) {
      int idx = t + i * 256;
      int r = idx >> 6, k = idx & 63;
      int gr = row0 + r;
      As[r][k] = (gr < M) ? A[(size_t)gr * 256 + k0 + k] : 0.f;
    }
    #pragma unroll
    for (int i = 0; i < 2; ++i) {
      int idx = t + i * 256;
      int k = idx >> 3, c4 = idx & 7;
      *reinterpret_cast<float4*>(&Bs[k][c4 * 4]) =
          *reinterpret_cast<const float4*>(&B[(size_t)(k0 + k) * 32 + c4 * 4]);
    }
    __syncthreads();
    #pragma unroll
    for (int k = 0; k < 64; k += 4) {
      float4 a[4], b[4];
      #pragma unroll
      for (int i = 0; i < 4; ++i)
        a[i] = *reinterpret_cast<const float4*>(&As[tr * 4 + i][k]);
      #pragma unroll
      for (int j = 0; j < 4; ++j)
        b[j] = *reinterpret_cast<const float4*>(&Bs[k + j][tc * 4]);
      #pragma unroll
      for (int i = 0; i < 4; ++i) {
        acc[i][0] += a[i].x * b[0].x + a[i].y * b[1].x + a[i].z * b[2].x + a[i].w * b[3].x;
        acc[i][1] += a[i].x * b[0].y + a[i].y * b[1].y + a[i].z * b[2].y + a[i].w * b[3].y;
        acc[i][2] += a[i].x * b[0].z + a[i].y * b[1].z + a[i].z * b[2].z + a[i].w * b[3].z;
        acc[i][3] += a[i].x * b[0].w + a[i].y * b[1].w + a[i].z * b[2].w + a[i].w * b[3].w;
      }
    }
  }
  #pragma unroll
  for (int i = 0; i < 4; ++i) {
    int gr = row0 + tr * 4 + i;
    if (gr < M) {
      float4 o = make_float4(acc[i][0], acc[i][1], acc[i][2], acc[i][3]);
      *reinterpret_cast<float4*>(&C[(size_t)gr * 32 + tc * 4]) = o;
    }
  }
}

// ------------- alpha0: per-node per-head dot(h0 row, a_src/a_dst) ----------
__global__ __launch_bounds__(256) void alpha0_kernel(
    const float* __restrict__ h0, const float* __restrict__ a_src,
    const float* __restrict__ a_dst, float* __restrict__ as_out,
    float* __restrict__ ad_out, int N) {
  const int lane = threadIdx.x & 63;
  const int wid = threadIdx.x >> 6;
  const int n = blockIdx.x * 4 + wid;
  if (n >= N) return;
  float4 v  = *reinterpret_cast<const float4*>(&h0[(size_t)n * 256 + lane * 4]);
  float4 s4 = *reinterpret_cast<const float4*>(&a_src[lane * 4]);
  float4 d4 = *reinterpret_cast<const float4*>(&a_dst[lane * 4]);
  float ps = v.x * s4.x + v.y * s4.y + v.z * s4.z + v.w * s4.w;
  float pd = v.x * d4.x + v.y * d4.y + v.z * d4.z + v.w * d4.w;
  #pragma unroll
  for (int off = 1; off < 16; off <<= 1) {
    ps += __shfl_xor(ps, off);
    pd += __shfl_xor(pd, off);
  }
  if ((lane & 15) == 0) {
    as_out[n * 4 + (lane >> 4)] = ps;
    ad_out[n * 4 + (lane >> 4)] = pd;
  }
}

// ------------- alpha1: per-node dot(h1 row[32], a_src1/a_dst1) -------------
__global__ __launch_bounds__(256) void alpha1_kernel(
    const float* __restrict__ h1, const float* __restrict__ a_src,
    const float* __restrict__ a_dst, float* __restrict__ as_out,
    float* __restrict__ ad_out, int N) {
  const int lane = threadIdx.x & 63;
  const int wid = threadIdx.x >> 6;
  const int n = blockIdx.x * 8 + wid * 2 + (lane >> 5);
  const int c = lane & 31;
  float ps = 0.f, pd = 0.f;
  if (n < N) {
    float v = h1[(size_t)n * 32 + c];
    ps = v * a_src[c];
    pd = v * a_dst[c];
  }
  #pragma unroll
  for (int off = 1; off < 32; off <<= 1) {
    ps += __shfl_xor(ps, off);
    pd += __shfl_xor(pd, off);
  }
  if (n < N && c == 0) { as_out[n] = ps; ad_out[n] = pd; }
}

// ------------------------- CSR build ---------------------------------------
__global__ __launch_bounds__(256) void hist_kernel(
    const int* __restrict__ dsts, int* __restrict__ deg, int E, int N) {
  int e = blockIdx.x * 256 + threadIdx.x;
  if (e >= E + N) return;
  int d = (e < E) ? dsts[e] : e - E;
  atomicAdd(&deg[d], 1);
}

// per-block exclusive scan (256 elems/block) + block sums
__global__ __launch_bounds__(256) void scan_block_kernel(
    const int* __restrict__ deg, int* __restrict__ excl,
    int* __restrict__ bsum, int N) {
  __shared__ int tmp[256];
  int i = blockIdx.x * 256 + threadIdx.x;
  int v = (i < N) ? deg[i] : 0;
  tmp[threadIdx.x] = v;
  __syncthreads();
  #pragma unroll
  for (int off = 1; off < 256; off <<= 1) {
    int t = (threadIdx.x >= off) ? tmp[threadIdx.x - off] : 0;
    __syncthreads();
    tmp[threadIdx.x] += t;
    __syncthreads();
  }
  if (i < N) excl[i] = tmp[threadIdx.x] - v;
  if (threadIdx.x == 255) bsum[blockIdx.x] = tmp[255];
}

// exclusive scan of block sums (single block; NB <= 256)
__global__ __launch_bounds__(256) void scan_bsum_kernel(int* __restrict__ bsum, int NB) {
  __shared__ int tmp[256];
  int i = threadIdx.x;
  int v = (i < NB) ? bsum[i] : 0;
  tmp[i] = v;
  __syncthreads();
  #pragma unroll
  for (int off = 1; off < 256; off <<= 1) {
    int t = (i >= off) ? tmp[i - off] : 0;
    __syncthreads();
    tmp[i] += t;
    __syncthreads();
  }
  if (i < NB) bsum[i] = tmp[i] - v;
}

__global__ __launch_bounds__(256) void scan_add_kernel(
    int* __restrict__ rowptr, const int* __restrict__ bsum,
    int* __restrict__ cursor, int N, int Etot) {
  int i = blockIdx.x * 256 + threadIdx.x;
  if (i < N) {
    int r = rowptr[i] + bsum[blockIdx.x];
    rowptr[i] = r;
    cursor[i] = r;
  }
  if (i == 0) rowptr[N] = Etot;
}

__global__ __launch_bounds__(256) void scatter_kernel(
    const int* __restrict__ srcs, const int* __restrict__ dsts,
    int* __restrict__ cursor, int* __restrict__ csr_src, int E, int N) {
  int e = blockIdx.x * 256 + threadIdx.x;
  if (e >= E + N) return;
  int s, d;
  if (e < E) { s = srcs[e]; d = dsts[e]; } else { s = d = e - E; }
  int pos = atomicAdd(&cursor[d], 1);
  csr_src[pos] = s;
}

// ------------- layer-0 aggregate: one wave per node ------------------------
// lane owns cols lane*4..lane*4+3; head h = lane>>4. Softmax max/denom are
// wave-local (every lane of a head group computes the same scalar chain).
// Fused: +b0, BN(eval), ReLU.
__global__ __launch_bounds__(256) void agg0_kernel(
    const int* __restrict__ rowptr, const int* __restrict__ csr_src,
    const float* __restrict__ h0, const float* __restrict__ as0,
    const float* __restrict__ ad0, const float* __restrict__ b0,
    const float* __restrict__ gamma, const float* __restrict__ beta,
    const float* __restrict__ mean, const float* __restrict__ var,
    float* __restrict__ out, int N) {
  const int lane = threadIdx.x & 63;
  const int wid = threadIdx.x >> 6;
  const int n = blockIdx.x * 4 + wid;
  if (n >= N) return;
  const int h = lane >> 4;
  const int beg = rowptr[n], end = rowptr[n + 1];
  const float adv = ad0[n * 4 + h];
  // pass 1: max score for this head
  float m = -1e30f;
  for (int i = beg; i < end; ++i) {
    int s = __builtin_nontemporal_load(&csr_src[i]);
    float x = as0[s * 4 + h] + adv;
    x = x > 0.f ? x : NEG_SLOPE * x;
    m = fmaxf(m, x);
  }
  // pass 2: weighted accumulate + denom
  float4 acc = make_float4(0.f, 0.f, 0.f, 0.f);
  float wsum = 0.f;
  for (int i = beg; i < end; ++i) {
    int s = csr_src[i];
    float x = as0[s * 4 + h] + adv;
    x = x > 0.f ? x : NEG_SLOPE * x;
    float w = __expf(x - m);
    wsum += w;
    float4 v = *reinterpret_cast<const float4*>(&h0[(size_t)s * 256 + lane * 4]);
    acc.x += w * v.x; acc.y += w * v.y; acc.z += w * v.z; acc.w += w * v.w;
  }
  float inv = 1.0f / wsum;
  // epilogue: bias + BN + ReLU
  int j = lane * 4;
  float4 bb = *reinterpret_cast<const float4*>(&b0[j]);
  float4 mu = *reinterpret_cast<const float4*>(&mean[j]);
  float4 gg = *reinterpret_cast<const float4*>(&gamma[j]);
  float4 vv = *reinterpret_cast<const float4*>(&var[j]);
  float4 be = *reinterpret_cast<const float4*>(&beta[j]);
  float4 o;
  o.x = (acc.x * inv + bb.x - mu.x) * (gg.x * rsqrtf(vv.x + BN_EPS)) + be.x;
  o.y = (acc.y * inv + bb.y - mu.y) * (gg.y * rsqrtf(vv.y + BN_EPS)) + be.y;
  o.z = (acc.z * inv + bb.z - mu.z) * (gg.z * rsqrtf(vv.z + BN_EPS)) + be.z;
  o.w = (acc.w * inv + bb.w - mu.w) * (gg.w * rsqrtf(vv.w + BN_EPS)) + be.w;
  o.x = fmaxf(o.x, 0.f); o.y = fmaxf(o.y, 0.f);
  o.z = fmaxf(o.z, 0.f); o.w = fmaxf(o.w, 0.f);
  *reinterpret_cast<float4*>(&out[(size_t)n * 256 + j]) = o;
}

// ------------- layer-1 aggregate: half-wave per node -----------------------
// lanes (lane&31) own one col each; 2 nodes/wave, 8 nodes/block.
// Fused: +b1, write node_embeddings, block-partial graph sum.
__global__ __launch_bounds__(256) void agg1_kernel(
    const int* __restrict__ rowptr, const int* __restrict__ csr_src,
    const float* __restrict__ h1, const float* __restrict__ as1,
    const float* __restrict__ ad1, const float* __restrict__ b1,
    float* __restrict__ out, float* __restrict__ gsum, int N) {
  __shared__ float red[8][32];
  const int t = threadIdx.x;
  const int c = t & 31;
  const int slot = t >> 5;
  const int n = blockIdx.x * 8 + slot;
  float val = 0.f;
  if (n < N) {
    const int beg = rowptr[n], end = rowptr[n + 1];
    const float adv = ad1[n];
    float m = -1e30f;
    for (int i = beg; i < end; ++i) {
      int s = csr_src[i];
      float x = as1[s] + adv;
      x = x > 0.f ? x : NEG_SLOPE * x;
      m = fmaxf(m, x);
    }
    float acc = 0.f, wsum = 0.f;
    for (int i = beg; i < end; ++i) {
      int s = csr_src[i];
      float x = as1[s] + adv;
      x = x > 0.f ? x : NEG_SLOPE * x;
      float w = __expf(x - m);
      wsum += w;
      acc += w * h1[(size_t)s * 32 + c];
    }
    val = acc / wsum + b1[c];
    out[(size_t)n * 32 + c] = val;
  }
  red[slot][c] = val;
  __syncthreads();
  if (t < 32) {
    float s = 0.f;
    #pragma unroll
    for (int i = 0; i < 8; ++i) s += red[i][t];
    atomicAdd(&gsum[t], s);
  }
}

// ------------- prediction head (1 block, 64 threads) -----------------------
__global__ void pred_kernel(
    const float* __restrict__ gsum, const float* __restrict__ hW1,
    const float* __restrict__ hb1, const float* __restrict__ hW2,
    const float* __restrict__ hb2, float* __restrict__ out, int N) {
  int j = threadIdx.x;
  float invN = 1.0f / (float)N;
  float acc = hb1[j];
  #pragma unroll
  for (int c = 0; c < 32; ++c) acc += (gsum[c] * invN) * hW1[c * 64 + j];
  acc = fmaxf(acc, 0.f);
  float v = acc * hW2[j];
  #pragma unroll
  for (int off = 1; off < 64; off <<= 1) v += __shfl_xor(v, off);
  if (j == 0) out[(size_t)N * 32] = v + hb2[0];
}

// ---------------------------------------------------------------------------
extern "C" void kernel_launch(void* const* d_in, const int* in_sizes, int n_in,
                              void* d_out, int out_size, void* d_ws, size_t ws_size,
                              hipStream_t stream) {
  const float* x       = (const float*)d_in[0];
  const int*   ei      = (const int*)d_in[1];
  const float* W0      = (const float*)d_in[2];
  const float* a_src0  = (const float*)d_in[3];
  const float* a_dst0  = (const float*)d_in[4];
  const float* b0      = (const float*)d_in[5];
  const float* bn_g    = (const float*)d_in[6];
  const float* bn_b    = (const float*)d_in[7];
  const float* bn_m    = (const float*)d_in[8];
  const float* bn_v    = (const float*)d_in[9];
  const float* W1      = (const float*)d_in[10];
  const float* a_src1  = (const float*)d_in[11];
  const float* a_dst1  = (const float*)d_in[12];
  const float* b1      = (const float*)d_in[13];
  const float* hW1     = (const float*)d_in[14];
  const float* hb1     = (const float*)d_in[15];
  const float* hW2     = (const float*)d_in[16];
  const float* hb2     = (const float*)d_in[17];

  const int N = in_sizes[0] / 128;
  const int E = in_sizes[1] / 2;
  const int Etot = E + N;
  const int* srcs = ei;
  const int* dsts = ei + E;
  const int NB = (N + 255) / 256;  // scan blocks (<= 256 required)

  float* out = (float*)d_out;

  // workspace layout (4-byte units)
  float* ws = (float*)d_ws;
  size_t off = 0;
  float* h0     = ws + off; off += (size_t)N * 256;
  float* agg0   = ws + off; off += (size_t)N * 256;
  float* h1     = ws + off; off += (size_t)N * 32;
  float* as0    = ws + off; off += (size_t)N * 4;
  float* ad0    = ws + off; off += (size_t)N * 4;
  float* as1    = ws + off; off += (size_t)N;
  float* ad1    = ws + off; off += (size_t)N;
  int* rowptr   = (int*)(ws + off); off += (size_t)N + 1;
  int* cursor   = (int*)(ws + off); off += (size_t)N;
  int* bsum     = (int*)(ws + off); off += 256;
  int* csr_src  = (int*)(ws + off); off += (size_t)Etot;
  // --- zeroed region (contiguous): deg + gsum ---
  size_t zoff = off;
  int* deg      = (int*)(ws + off); off += (size_t)N;
  float* gsum   = ws + off; off += 32;

  hipMemsetAsync(ws + zoff, 0, (off - zoff) * sizeof(float), stream);

  auto cdiv = [](long a, long b) { return (int)((a + b - 1) / b); };

  // CSR build (graph-only; independent of features)
  hist_kernel<<<cdiv(Etot, 256), 256, 0, stream>>>(dsts, deg, E, N);
  scan_block_kernel<<<NB, 256, 0, stream>>>(deg, rowptr, bsum, N);
  scan_bsum_kernel<<<1, 256, 0, stream>>>(bsum, NB);
  scan_add_kernel<<<NB, 256, 0, stream>>>(rowptr, bsum, cursor, N, Etot);
  scatter_kernel<<<cdiv(Etot, 256), 256, 0, stream>>>(srcs, dsts, cursor, csr_src, E, N);

  // layer 0
  gemm0_kernel<<<dim3(cdiv(N, 64), 4), 256, 0, stream>>>(x, W0, h0, N);
  alpha0_kernel<<<cdiv(N, 4), 256, 0, stream>>>(h0, a_src0, a_dst0, as0, ad0, N);
  agg0_kernel<<<cdiv(N, 4), 256, 0, stream>>>(rowptr, csr_src, h0, as0, ad0,
                                              b0, bn_g, bn_b, bn_m, bn_v, agg0, N);

  // layer 1
  gemm1_kernel<<<cdiv(N, 128), 256, 0, stream>>>(agg0, W1, h1, N);
  alpha1_kernel<<<cdiv(N, 8), 256, 0, stream>>>(h1, a_src1, a_dst1, as1, ad1, N);
  agg1_kernel<<<cdiv(N, 8), 256, 0, stream>>>(rowptr, csr_src, h1, as1, ad1,
                                              b1, out, gsum, N);

  // head
  pred_kernel<<<1, 64, 0, stream>>>(gsum, hW1, hb1, hW2, hb2, out, N);
}

// Round 3
// 593.906 us; speedup vs baseline: 2.8112x; 1.3368x over previous
//
#include <hip/hip_runtime.h>

// ---------------------------------------------------------------------------
// SupervisedGATEncoder: 2-layer GAT (4 heads x 64 -> BN -> ReLU -> 1 head x 32)
// + graph-mean prediction head.
//
// R3: (a) agg0/agg1 single-pass softmax without max-subtraction (scores are
// O(1), exp is fp32-safe; alpha ratio unchanged); (b) h0 stored bf16 to halve
// the dominant random-gather traffic; (c) alpha dots fused into GEMM epilogues
// (gemm0 col-block == head). CSR build unchanged.
// ---------------------------------------------------------------------------

#define NEG_SLOPE 0.2f
#define BN_EPS 1e-5f

__device__ __forceinline__ float bf2f(unsigned short u) {
  return __uint_as_float((unsigned)u << 16);
}
__device__ __forceinline__ unsigned short f2bf(float f) {
  unsigned u = __float_as_uint(f);
  u += 0x7fff + ((u >> 16) & 1);   // round-to-nearest-even
  return (unsigned short)(u >> 16);
}

// ---------------- GEMM0: h0[M,256] = x[M,128] @ W0[128,256], bf16 out ------
// + fused alpha0: as0/ad0[n,head] = dot(h0 row slice, a_src0/a_dst0[head])
// blockIdx.y == head (64-col block). Thread computes 4x4.
__global__ __launch_bounds__(256) void gemm0_kernel(
    const float* __restrict__ A, const float* __restrict__ B,
    const float* __restrict__ a_src0, const float* __restrict__ a_dst0,
    unsigned short* __restrict__ h0bf, float* __restrict__ as0,
    float* __restrict__ ad0, int M) {
  __shared__ float As[64][68];
  __shared__ float Bs[64][64];
  const int t = threadIdx.x;
  const int row0 = blockIdx.x * 64;
  const int hy = blockIdx.y;          // head
  const int col0 = hy * 64;
  const int tr = t >> 4;
  const int tc = t & 15;
  float acc[4][4] = {};
  for (int k0 = 0; k0 < 128; k0 += 64) {
    __syncthreads();
    #pragma unroll
    for (int i = 0; i < 16; ++i) {
      int idx = t + i * 256;
      int r = idx >> 6, k = idx & 63;
      int gr = row0 + r;
      As[r][k] = (gr < M) ? A[(size_t)gr * 128 + k0 + k] : 0.f;
    }
    #pragma unroll
    for (int i = 0; i < 4; ++i) {
      int idx = t + i * 256;
      int k = idx >> 4, c4 = idx & 15;
      *reinterpret_cast<float4*>(&Bs[k][c4 * 4]) =
          *reinterpret_cast<const float4*>(&B[(size_t)(k0 + k) * 256 + col0 + c4 * 4]);
    }
    __syncthreads();
    #pragma unroll
    for (int k = 0; k < 64; k += 4) {
      float4 a[4], b[4];
      #pragma unroll
      for (int i = 0; i < 4; ++i)
        a[i] = *reinterpret_cast<const float4*>(&As[tr * 4 + i][k]);
      #pragma unroll
      for (int j = 0; j < 4; ++j)
        b[j] = *reinterpret_cast<const float4*>(&Bs[k + j][tc * 4]);
      #pragma unroll
      for (int i = 0; i < 4; ++i) {
        acc[i][0] += a[i].x * b[0].x + a[i].y * b[1].x + a[i].z * b[2].x + a[i].w * b[3].x;
        acc[i][1] += a[i].x * b[0].y + a[i].y * b[1].y + a[i].z * b[2].y + a[i].w * b[3].y;
        acc[i][2] += a[i].x * b[0].z + a[i].y * b[1].z + a[i].z * b[2].z + a[i].w * b[3].z;
        acc[i][3] += a[i].x * b[0].w + a[i].y * b[1].w + a[i].z * b[2].w + a[i].w * b[3].w;
      }
    }
  }
  // attention vectors for this thread's 4 columns (uniform over rows)
  float av[4], dv[4];
  #pragma unroll
  for (int j = 0; j < 4; ++j) {
    av[j] = a_src0[hy * 64 + tc * 4 + j];
    dv[j] = a_dst0[hy * 64 + tc * 4 + j];
  }
  #pragma unroll
  for (int i = 0; i < 4; ++i) {
    int gr = row0 + tr * 4 + i;
    float ps = acc[i][0] * av[0] + acc[i][1] * av[1] + acc[i][2] * av[2] + acc[i][3] * av[3];
    float pd = acc[i][0] * dv[0] + acc[i][1] * dv[1] + acc[i][2] * dv[2] + acc[i][3] * dv[3];
    #pragma unroll
    for (int off = 1; off < 16; off <<= 1) {
      ps += __shfl_xor(ps, off);
      pd += __shfl_xor(pd, off);
    }
    if (gr < M) {
      ushort4 o;
      o.x = f2bf(acc[i][0]); o.y = f2bf(acc[i][1]);
      o.z = f2bf(acc[i][2]); o.w = f2bf(acc[i][3]);
      *reinterpret_cast<ushort4*>(&h0bf[(size_t)gr * 256 + col0 + tc * 4]) = o;
      if (tc == 0) { as0[gr * 4 + hy] = ps; ad0[gr * 4 + hy] = pd; }
    }
  }
}

// ---------------- GEMM1: h1[M,32] = agg0[M,256] @ W1[256,32] ---------------
// + fused alpha1 (full-row dot, 8-lane reduce)
__global__ __launch_bounds__(256) void gemm1_kernel(
    const float* __restrict__ A, const float* __restrict__ B,
    const float* __restrict__ a_src1, const float* __restrict__ a_dst1,
    float* __restrict__ C, float* __restrict__ as1, float* __restrict__ ad1,
    int M) {
  __shared__ float As[128][68];
  __shared__ float Bs[64][32];
  const int t = threadIdx.x;
  const int row0 = blockIdx.x * 128;
  const int tr = t >> 3;
  const int tc = t & 7;
  float acc[4][4] = {};
  for (int k0 = 0; k0 < 256; k0 += 64) {
    __syncthreads();
    #pragma unroll
    for (int i = 0; i < 32; ++i) {
      int idx = t + i * 256;
      int r = idx >> 6, k = idx & 63;
      int gr = row0 + r;
      As[r][k] = (gr < M) ? A[(size_t)gr * 256 + k0 + k] : 0.f;
    }
    #pragma unroll
    for (int i = 0; i < 2; ++i) {
      int idx = t + i * 256;
      int k = idx >> 3, c4 = idx & 7;
      *reinterpret_cast<float4*>(&Bs[k][c4 * 4]) =
          *reinterpret_cast<const float4*>(&B[(size_t)(k0 + k) * 32 + c4 * 4]);
    }
    __syncthreads();
    #pragma unroll
    for (int k = 0; k < 64; k += 4) {
      float4 a[4], b[4];
      #pragma unroll
      for (int i = 0; i < 4; ++i)
        a[i] = *reinterpret_cast<const float4*>(&As[tr * 4 + i][k]);
      #pragma unroll
      for (int j = 0; j < 4; ++j)
        b[j] = *reinterpret_cast<const float4*>(&Bs[k + j][tc * 4]);
      #pragma unroll
      for (int i = 0; i < 4; ++i) {
        acc[i][0] += a[i].x * b[0].x + a[i].y * b[1].x + a[i].z * b[2].x + a[i].w * b[3].x;
        acc[i][1] += a[i].x * b[0].y + a[i].y * b[1].y + a[i].z * b[2].y + a[i].w * b[3].y;
        acc[i][2] += a[i].x * b[0].z + a[i].y * b[1].z + a[i].z * b[2].z + a[i].w * b[3].z;
        acc[i][3] += a[i].x * b[0].w + a[i].y * b[1].w + a[i].z * b[2].w + a[i].w * b[3].w;
      }
    }
  }
  float av[4], dv[4];
  #pragma unroll
  for (int j = 0; j < 4; ++j) {
    av[j] = a_src1[tc * 4 + j];
    dv[j] = a_dst1[tc * 4 + j];
  }
  #pragma unroll
  for (int i = 0; i < 4; ++i) {
    int gr = row0 + tr * 4 + i;
    float ps = acc[i][0] * av[0] + acc[i][1] * av[1] + acc[i][2] * av[2] + acc[i][3] * av[3];
    float pd = acc[i][0] * dv[0] + acc[i][1] * dv[1] + acc[i][2] * dv[2] + acc[i][3] * dv[3];
    #pragma unroll
    for (int off = 1; off < 8; off <<= 1) {
      ps += __shfl_xor(ps, off);
      pd += __shfl_xor(pd, off);
    }
    if (gr < M) {
      float4 o = make_float4(acc[i][0], acc[i][1], acc[i][2], acc[i][3]);
      *reinterpret_cast<float4*>(&C[(size_t)gr * 32 + tc * 4]) = o;
      if (tc == 0) { as1[gr] = ps; ad1[gr] = pd; }
    }
  }
}

// ------------------------- CSR build ---------------------------------------
__global__ __launch_bounds__(256) void hist_kernel(
    const int* __restrict__ dsts, int* __restrict__ deg, int E, int N) {
  int e = blockIdx.x * 256 + threadIdx.x;
  if (e >= E + N) return;
  int d = (e < E) ? dsts[e] : e - E;
  atomicAdd(&deg[d], 1);
}

__global__ __launch_bounds__(256) void scan_block_kernel(
    const int* __restrict__ deg, int* __restrict__ excl,
    int* __restrict__ bsum, int N) {
  __shared__ int tmp[256];
  int i = blockIdx.x * 256 + threadIdx.x;
  int v = (i < N) ? deg[i] : 0;
  tmp[threadIdx.x] = v;
  __syncthreads();
  #pragma unroll
  for (int off = 1; off < 256; off <<= 1) {
    int t = (threadIdx.x >= off) ? tmp[threadIdx.x - off] : 0;
    __syncthreads();
    tmp[threadIdx.x] += t;
    __syncthreads();
  }
  if (i < N) excl[i] = tmp[threadIdx.x] - v;
  if (threadIdx.x == 255) bsum[blockIdx.x] = tmp[255];
}

__global__ __launch_bounds__(256) void scan_bsum_kernel(int* __restrict__ bsum, int NB) {
  __shared__ int tmp[256];
  int i = threadIdx.x;
  int v = (i < NB) ? bsum[i] : 0;
  tmp[i] = v;
  __syncthreads();
  #pragma unroll
  for (int off = 1; off < 256; off <<= 1) {
    int t = (i >= off) ? tmp[i - off] : 0;
    __syncthreads();
    tmp[i] += t;
    __syncthreads();
  }
  if (i < NB) bsum[i] = tmp[i] - v;
}

__global__ __launch_bounds__(256) void scan_add_kernel(
    int* __restrict__ rowptr, const int* __restrict__ bsum,
    int* __restrict__ cursor, int N, int Etot) {
  int i = blockIdx.x * 256 + threadIdx.x;
  if (i < N) {
    int r = rowptr[i] + bsum[blockIdx.x];
    rowptr[i] = r;
    cursor[i] = r;
  }
  if (i == 0) rowptr[N] = Etot;
}

__global__ __launch_bounds__(256) void scatter_kernel(
    const int* __restrict__ srcs, const int* __restrict__ dsts,
    int* __restrict__ cursor, int* __restrict__ csr_src, int E, int N) {
  int e = blockIdx.x * 256 + threadIdx.x;
  if (e >= E + N) return;
  int s, d;
  if (e < E) { s = srcs[e]; d = dsts[e]; } else { s = d = e - E; }
  int pos = atomicAdd(&cursor[d], 1);
  csr_src[pos] = s;
}

// ------------- layer-0 aggregate: one wave per node, single pass -----------
// No max-subtraction (scores O(1); exp fp32-safe; alpha ratio identical).
// h0 gathered in bf16, accumulated fp32. Fused +b0, BN(eval), ReLU.
__global__ __launch_bounds__(256) void agg0_kernel(
    const int* __restrict__ rowptr, const int* __restrict__ csr_src,
    const unsigned short* __restrict__ h0bf, const float* __restrict__ as0,
    const float* __restrict__ ad0, const float* __restrict__ b0,
    const float* __restrict__ gamma, const float* __restrict__ beta,
    const float* __restrict__ mean, const float* __restrict__ var,
    float* __restrict__ out, int N) {
  const int lane = threadIdx.x & 63;
  const int wid = threadIdx.x >> 6;
  const int n = blockIdx.x * 4 + wid;
  if (n >= N) return;
  const int h = lane >> 4;
  const int beg = rowptr[n], end = rowptr[n + 1];
  const float adv = ad0[n * 4 + h];
  float4 acc = make_float4(0.f, 0.f, 0.f, 0.f);
  float wsum = 0.f;
  for (int i = beg; i < end; ++i) {
    int s = csr_src[i];
    float x = as0[s * 4 + h] + adv;
    x = x > 0.f ? x : NEG_SLOPE * x;
    float w = __expf(x);
    wsum += w;
    ushort4 v = *reinterpret_cast<const ushort4*>(&h0bf[(size_t)s * 256 + lane * 4]);
    acc.x += w * bf2f(v.x);
    acc.y += w * bf2f(v.y);
    acc.z += w * bf2f(v.z);
    acc.w += w * bf2f(v.w);
  }
  float inv = 1.0f / wsum;
  int j = lane * 4;
  float4 bb = *reinterpret_cast<const float4*>(&b0[j]);
  float4 mu = *reinterpret_cast<const float4*>(&mean[j]);
  float4 gg = *reinterpret_cast<const float4*>(&gamma[j]);
  float4 vv = *reinterpret_cast<const float4*>(&var[j]);
  float4 be = *reinterpret_cast<const float4*>(&beta[j]);
  float4 o;
  o.x = (acc.x * inv + bb.x - mu.x) * (gg.x * rsqrtf(vv.x + BN_EPS)) + be.x;
  o.y = (acc.y * inv + bb.y - mu.y) * (gg.y * rsqrtf(vv.y + BN_EPS)) + be.y;
  o.z = (acc.z * inv + bb.z - mu.z) * (gg.z * rsqrtf(vv.z + BN_EPS)) + be.z;
  o.w = (acc.w * inv + bb.w - mu.w) * (gg.w * rsqrtf(vv.w + BN_EPS)) + be.w;
  o.x = fmaxf(o.x, 0.f); o.y = fmaxf(o.y, 0.f);
  o.z = fmaxf(o.z, 0.f); o.w = fmaxf(o.w, 0.f);
  *reinterpret_cast<float4*>(&out[(size_t)n * 256 + j]) = o;
}

// ------------- layer-1 aggregate: half-wave per node, single pass ----------
// Fused: +b1, write node_embeddings, block-partial graph sum.
__global__ __launch_bounds__(256) void agg1_kernel(
    const int* __restrict__ rowptr, const int* __restrict__ csr_src,
    const float* __restrict__ h1, const float* __restrict__ as1,
    const float* __restrict__ ad1, const float* __restrict__ b1,
    float* __restrict__ out, float* __restrict__ gsum, int N) {
  __shared__ float red[8][32];
  const int t = threadIdx.x;
  const int c = t & 31;
  const int slot = t >> 5;
  const int n = blockIdx.x * 8 + slot;
  float val = 0.f;
  if (n < N) {
    const int beg = rowptr[n], end = rowptr[n + 1];
    const float adv = ad1[n];
    float acc = 0.f, wsum = 0.f;
    for (int i = beg; i < end; ++i) {
      int s = csr_src[i];
      float x = as1[s] + adv;
      x = x > 0.f ? x : NEG_SLOPE * x;
      float w = __expf(x);
      wsum += w;
      acc += w * h1[(size_t)s * 32 + c];
    }
    val = acc / wsum + b1[c];
    out[(size_t)n * 32 + c] = val;
  }
  red[slot][c] = val;
  __syncthreads();
  if (t < 32) {
    float s = 0.f;
    #pragma unroll
    for (int i = 0; i < 8; ++i) s += red[i][t];
    atomicAdd(&gsum[t], s);
  }
}

// ------------- prediction head (1 block, 64 threads) -----------------------
__global__ void pred_kernel(
    const float* __restrict__ gsum, const float* __restrict__ hW1,
    const float* __restrict__ hb1, const float* __restrict__ hW2,
    const float* __restrict__ hb2, float* __restrict__ out, int N) {
  int j = threadIdx.x;
  float invN = 1.0f / (float)N;
  float acc = hb1[j];
  #pragma unroll
  for (int c = 0; c < 32; ++c) acc += (gsum[c] * invN) * hW1[c * 64 + j];
  acc = fmaxf(acc, 0.f);
  float v = acc * hW2[j];
  #pragma unroll
  for (int off = 1; off < 64; off <<= 1) v += __shfl_xor(v, off);
  if (j == 0) out[(size_t)N * 32] = v + hb2[0];
}

// ---------------------------------------------------------------------------
extern "C" void kernel_launch(void* const* d_in, const int* in_sizes, int n_in,
                              void* d_out, int out_size, void* d_ws, size_t ws_size,
                              hipStream_t stream) {
  const float* x       = (const float*)d_in[0];
  const int*   ei      = (const int*)d_in[1];
  const float* W0      = (const float*)d_in[2];
  const float* a_src0  = (const float*)d_in[3];
  const float* a_dst0  = (const float*)d_in[4];
  const float* b0      = (const float*)d_in[5];
  const float* bn_g    = (const float*)d_in[6];
  const float* bn_b    = (const float*)d_in[7];
  const float* bn_m    = (const float*)d_in[8];
  const float* bn_v    = (const float*)d_in[9];
  const float* W1      = (const float*)d_in[10];
  const float* a_src1  = (const float*)d_in[11];
  const float* a_dst1  = (const float*)d_in[12];
  const float* b1      = (const float*)d_in[13];
  const float* hW1     = (const float*)d_in[14];
  const float* hb1     = (const float*)d_in[15];
  const float* hW2     = (const float*)d_in[16];
  const float* hb2     = (const float*)d_in[17];

  const int N = in_sizes[0] / 128;
  const int E = in_sizes[1] / 2;
  const int Etot = E + N;
  const int* srcs = ei;
  const int* dsts = ei + E;
  const int NB = (N + 255) / 256;

  float* out = (float*)d_out;

  // workspace layout (4-byte units)
  float* ws = (float*)d_ws;
  size_t off = 0;
  unsigned short* h0bf = (unsigned short*)(ws + off); off += (size_t)N * 128;  // N*256 bf16
  float* agg0   = ws + off; off += (size_t)N * 256;
  float* h1     = ws + off; off += (size_t)N * 32;
  float* as0    = ws + off; off += (size_t)N * 4;
  float* ad0    = ws + off; off += (size_t)N * 4;
  float* as1    = ws + off; off += (size_t)N;
  float* ad1    = ws + off; off += (size_t)N;
  int* rowptr   = (int*)(ws + off); off += (size_t)N + 1;
  int* cursor   = (int*)(ws + off); off += (size_t)N;
  int* bsum     = (int*)(ws + off); off += 256;
  int* csr_src  = (int*)(ws + off); off += (size_t)Etot;
  // --- zeroed region (contiguous): deg + gsum ---
  size_t zoff = off;
  int* deg      = (int*)(ws + off); off += (size_t)N;
  float* gsum   = ws + off; off += 32;

  hipMemsetAsync(ws + zoff, 0, (off - zoff) * sizeof(float), stream);

  auto cdiv = [](long a, long b) { return (int)((a + b - 1) / b); };

  // CSR build (graph-only)
  hist_kernel<<<cdiv(Etot, 256), 256, 0, stream>>>(dsts, deg, E, N);
  scan_block_kernel<<<NB, 256, 0, stream>>>(deg, rowptr, bsum, N);
  scan_bsum_kernel<<<1, 256, 0, stream>>>(bsum, NB);
  scan_add_kernel<<<NB, 256, 0, stream>>>(rowptr, bsum, cursor, N, Etot);
  scatter_kernel<<<cdiv(Etot, 256), 256, 0, stream>>>(srcs, dsts, cursor, csr_src, E, N);

  // layer 0
  gemm0_kernel<<<dim3(cdiv(N, 64), 4), 256, 0, stream>>>(
      x, W0, a_src0, a_dst0, h0bf, as0, ad0, N);
  agg0_kernel<<<cdiv(N, 4), 256, 0, stream>>>(rowptr, csr_src, h0bf, as0, ad0,
                                              b0, bn_g, bn_b, bn_m, bn_v, agg0, N);

  // layer 1
  gemm1_kernel<<<cdiv(N, 128), 256, 0, stream>>>(
      agg0, W1, a_src1, a_dst1, h1, as1, ad1, N);
  agg1_kernel<<<cdiv(N, 8), 256, 0, stream>>>(rowptr, csr_src, h1, as1, ad1,
                                              b1, out, gsum, N);

  // head
  pred_kernel<<<1, 64, 0, stream>>>(gsum, hW1, hb1, hW2, hb2, out, N);
}

// Round 4
// 512.941 us; speedup vs baseline: 3.2550x; 1.1578x over previous
//
#include <hip/hip_runtime.h>

// ---------------------------------------------------------------------------
// SupervisedGATEncoder: 2-layer GAT (4 heads x 64 -> BN -> ReLU -> 1 head x 32)
// + graph-mean prediction head.
//
// R4: gemm0 -> bf16 MFMA (16x16x32). W0 pre-swizzled into B-fragment order
// (global, L2-hot); x staged fp32->bf16 into LDS in A-fragment order
// (conflict-free ds_read_b128). Alpha0 dot fused in MFMA epilogue.
// agg0/agg1 single-pass softmax (no max shift), h0 bf16 gather. CSR build
// unchanged. gemm1 stays fp32 VALU.
// ---------------------------------------------------------------------------

#define NEG_SLOPE 0.2f
#define BN_EPS 1e-5f

typedef __attribute__((ext_vector_type(8))) short bf16x8;
typedef __attribute__((ext_vector_type(4))) float f32x4;

__device__ __forceinline__ float bf2f(unsigned short u) {
  return __uint_as_float((unsigned)u << 16);
}
__device__ __forceinline__ unsigned short f2bf(float f) {
  unsigned u = __float_as_uint(f);
  u += 0x7fff + ((u >> 16) & 1);   // round-to-nearest-even
  return (unsigned short)(u >> 16);
}

// ---------------- W0 -> bf16, swizzled to MFMA B-fragment order ------------
// w0sw[((h*4+ci)*4+ks)*64 + lane][j] = W0[ks*32 + (lane>>4)*8 + j][h*64+ci*16+(lane&15)]
__global__ __launch_bounds__(256) void w0_swizzle_kernel(
    const float* __restrict__ W0, unsigned short* __restrict__ w0sw) {
  int o = blockIdx.x * 256 + threadIdx.x;   // 32768 total
  int j = o & 7, l = (o >> 3) & 63, ks = (o >> 9) & 3,
      ci = (o >> 11) & 3, h = (o >> 13) & 3;
  int row = ks * 32 + (l >> 4) * 8 + j;
  int col = h * 64 + ci * 16 + (l & 15);
  w0sw[o] = f2bf(W0[row * 256 + col]);
}

// ---------------- GEMM0 (MFMA): h0[M,256] = x[M,128] @ W0[128,256] ---------
// block: 256 thr = 4 waves; wave w computes rows row0..row0+63 x head-w cols.
// + fused alpha0 epilogue; h0 stored bf16.
__global__ __launch_bounds__(256) void gemm0_mfma_kernel(
    const float* __restrict__ x, const unsigned short* __restrict__ w0sw,
    const float* __restrict__ a_src0, const float* __restrict__ a_dst0,
    unsigned short* __restrict__ h0bf, float* __restrict__ as0,
    float* __restrict__ ad0, int M) {
  __shared__ unsigned short Asw[16 * 64 * 8];   // 16 KB: [slot=ri*4+ks][lane][8]
  const int t = threadIdx.x;
  const int lane = t & 63;
  const int h = t >> 6;            // wave id == head
  const int row0 = blockIdx.x * 64;

  // ---- stage A: x fp32 -> bf16, A-fragment order ----
  #pragma unroll
  for (int i = 0; i < 8; ++i) {
    int q = t + 256 * i;           // 2048 float4 chunks: 64 rows x 32
    int r = q >> 5, c4 = q & 31;
    int gr = row0 + r;
    float4 v = make_float4(0.f, 0.f, 0.f, 0.f);
    if (gr < M) v = *reinterpret_cast<const float4*>(&x[(size_t)gr * 128 + c4 * 4]);
    int ks = c4 >> 3;
    int lane_hi = (c4 >> 1) & 3;
    int j0 = (c4 & 1) * 4;
    int slot = (r >> 4) * 4 + ks;
    int dlane = (r & 15) + 16 * lane_hi;
    ushort4 o;
    o.x = f2bf(v.x); o.y = f2bf(v.y); o.z = f2bf(v.z); o.w = f2bf(v.w);
    *reinterpret_cast<ushort4*>(&Asw[(slot * 64 + dlane) * 8 + j0]) = o;
  }
  __syncthreads();

  // ---- MFMA main loop ----
  f32x4 acc[4][4] = {};            // [ri][ci]
  const bf16x8* wp = reinterpret_cast<const bf16x8*>(w0sw);
  #pragma unroll
  for (int ks = 0; ks < 4; ++ks) {
    bf16x8 bfrag[4];
    #pragma unroll
    for (int ci = 0; ci < 4; ++ci)
      bfrag[ci] = wp[(h * 16 + ci * 4 + ks) * 64 + lane];
    #pragma unroll
    for (int ri = 0; ri < 4; ++ri) {
      bf16x8 af = *reinterpret_cast<const bf16x8*>(&Asw[((ri * 4 + ks) * 64 + lane) * 8]);
      #pragma unroll
      for (int ci = 0; ci < 4; ++ci)
        acc[ri][ci] = __builtin_amdgcn_mfma_f32_16x16x32_bf16(af, bfrag[ci], acc[ri][ci], 0, 0, 0);
    }
  }

  // ---- epilogue: store h0 (bf16) + fused alpha dots ----
  float av[4], dv[4];
  #pragma unroll
  for (int ci = 0; ci < 4; ++ci) {
    av[ci] = a_src0[h * 64 + ci * 16 + (lane & 15)];
    dv[ci] = a_dst0[h * 64 + ci * 16 + (lane & 15)];
  }
  const int mrow = (lane >> 4) * 4;
  #pragma unroll
  for (int ri = 0; ri < 4; ++ri) {
    #pragma unroll
    for (int r = 0; r < 4; ++r) {
      int gr = row0 + ri * 16 + mrow + r;
      float ps = acc[ri][0][r] * av[0] + acc[ri][1][r] * av[1] +
                 acc[ri][2][r] * av[2] + acc[ri][3][r] * av[3];
      float pd = acc[ri][0][r] * dv[0] + acc[ri][1][r] * dv[1] +
                 acc[ri][2][r] * dv[2] + acc[ri][3][r] * dv[3];
      #pragma unroll
      for (int off = 1; off < 16; off <<= 1) {
        ps += __shfl_xor(ps, off);
        pd += __shfl_xor(pd, off);
      }
      if (gr < M) {
        #pragma unroll
        for (int ci = 0; ci < 4; ++ci)
          h0bf[(size_t)gr * 256 + h * 64 + ci * 16 + (lane & 15)] = f2bf(acc[ri][ci][r]);
        if ((lane & 15) == 0) { as0[gr * 4 + h] = ps; ad0[gr * 4 + h] = pd; }
      }
    }
  }
}

// ---------------- GEMM1: h1[M,32] = agg0[M,256] @ W1[256,32] ---------------
// + fused alpha1 (full-row dot, 8-lane reduce)
__global__ __launch_bounds__(256) void gemm1_kernel(
    const float* __restrict__ A, const float* __restrict__ B,
    const float* __restrict__ a_src1, const float* __restrict__ a_dst1,
    float* __restrict__ C, float* __restrict__ as1, float* __restrict__ ad1,
    int M) {
  __shared__ float As[128][68];
  __shared__ float Bs[64][32];
  const int t = threadIdx.x;
  const int row0 = blockIdx.x * 128;
  const int tr = t >> 3;
  const int tc = t & 7;
  float acc[4][4] = {};
  for (int k0 = 0; k0 < 256; k0 += 64) {
    __syncthreads();
    #pragma unroll
    for (int i = 0; i < 32; ++i) {
      int idx = t + i * 256;
      int r = idx >> 6, k = idx & 63;
      int gr = row0 + r;
      As[r][k] = (gr < M) ? A[(size_t)gr * 256 + k0 + k] : 0.f;
    }
    #pragma unroll
    for (int i = 0; i < 2; ++i) {
      int idx = t + i * 256;
      int k = idx >> 3, c4 = idx & 7;
      *reinterpret_cast<float4*>(&Bs[k][c4 * 4]) =
          *reinterpret_cast<const float4*>(&B[(size_t)(k0 + k) * 32 + c4 * 4]);
    }
    __syncthreads();
    #pragma unroll
    for (int k = 0; k < 64; k += 4) {
      float4 a[4], b[4];
      #pragma unroll
      for (int i = 0; i < 4; ++i)
        a[i] = *reinterpret_cast<const float4*>(&As[tr * 4 + i][k]);
      #pragma unroll
      for (int j = 0; j < 4; ++j)
        b[j] = *reinterpret_cast<const float4*>(&Bs[k + j][tc * 4]);
      #pragma unroll
      for (int i = 0; i < 4; ++i) {
        acc[i][0] += a[i].x * b[0].x + a[i].y * b[1].x + a[i].z * b[2].x + a[i].w * b[3].x;
        acc[i][1] += a[i].x * b[0].y + a[i].y * b[1].y + a[i].z * b[2].y + a[i].w * b[3].y;
        acc[i][2] += a[i].x * b[0].z + a[i].y * b[1].z + a[i].z * b[2].z + a[i].w * b[3].z;
        acc[i][3] += a[i].x * b[0].w + a[i].y * b[1].w + a[i].z * b[2].w + a[i].w * b[3].w;
      }
    }
  }
  float av[4], dv[4];
  #pragma unroll
  for (int j = 0; j < 4; ++j) {
    av[j] = a_src1[tc * 4 + j];
    dv[j] = a_dst1[tc * 4 + j];
  }
  #pragma unroll
  for (int i = 0; i < 4; ++i) {
    int gr = row0 + tr * 4 + i;
    float ps = acc[i][0] * av[0] + acc[i][1] * av[1] + acc[i][2] * av[2] + acc[i][3] * av[3];
    float pd = acc[i][0] * dv[0] + acc[i][1] * dv[1] + acc[i][2] * dv[2] + acc[i][3] * dv[3];
    #pragma unroll
    for (int off = 1; off < 8; off <<= 1) {
      ps += __shfl_xor(ps, off);
      pd += __shfl_xor(pd, off);
    }
    if (gr < M) {
      float4 o = make_float4(acc[i][0], acc[i][1], acc[i][2], acc[i][3]);
      *reinterpret_cast<float4*>(&C[(size_t)gr * 32 + tc * 4]) = o;
      if (tc == 0) { as1[gr] = ps; ad1[gr] = pd; }
    }
  }
}

// ------------------------- CSR build ---------------------------------------
__global__ __launch_bounds__(256) void hist_kernel(
    const int* __restrict__ dsts, int* __restrict__ deg, int E, int N) {
  int e = blockIdx.x * 256 + threadIdx.x;
  if (e >= E + N) return;
  int d = (e < E) ? dsts[e] : e - E;
  atomicAdd(&deg[d], 1);
}

__global__ __launch_bounds__(256) void scan_block_kernel(
    const int* __restrict__ deg, int* __restrict__ excl,
    int* __restrict__ bsum, int N) {
  __shared__ int tmp[256];
  int i = blockIdx.x * 256 + threadIdx.x;
  int v = (i < N) ? deg[i] : 0;
  tmp[threadIdx.x] = v;
  __syncthreads();
  #pragma unroll
  for (int off = 1; off < 256; off <<= 1) {
    int t = (threadIdx.x >= off) ? tmp[threadIdx.x - off] : 0;
    __syncthreads();
    tmp[threadIdx.x] += t;
    __syncthreads();
  }
  if (i < N) excl[i] = tmp[threadIdx.x] - v;
  if (threadIdx.x == 255) bsum[blockIdx.x] = tmp[255];
}

__global__ __launch_bounds__(256) void scan_bsum_kernel(int* __restrict__ bsum, int NB) {
  __shared__ int tmp[256];
  int i = threadIdx.x;
  int v = (i < NB) ? bsum[i] : 0;
  tmp[i] = v;
  __syncthreads();
  #pragma unroll
  for (int off = 1; off < 256; off <<= 1) {
    int t = (i >= off) ? tmp[i - off] : 0;
    __syncthreads();
    tmp[i] += t;
    __syncthreads();
  }
  if (i < NB) bsum[i] = tmp[i] - v;
}

__global__ __launch_bounds__(256) void scan_add_kernel(
    int* __restrict__ rowptr, const int* __restrict__ bsum,
    int* __restrict__ cursor, int N, int Etot) {
  int i = blockIdx.x * 256 + threadIdx.x;
  if (i < N) {
    int r = rowptr[i] + bsum[blockIdx.x];
    rowptr[i] = r;
    cursor[i] = r;
  }
  if (i == 0) rowptr[N] = Etot;
}

__global__ __launch_bounds__(256) void scatter_kernel(
    const int* __restrict__ srcs, const int* __restrict__ dsts,
    int* __restrict__ cursor, int* __restrict__ csr_src, int E, int N) {
  int e = blockIdx.x * 256 + threadIdx.x;
  if (e >= E + N) return;
  int s, d;
  if (e < E) { s = srcs[e]; d = dsts[e]; } else { s = d = e - E; }
  int pos = atomicAdd(&cursor[d], 1);
  csr_src[pos] = s;
}

// ------------- layer-0 aggregate: one wave per node, single pass -----------
__global__ __launch_bounds__(256) void agg0_kernel(
    const int* __restrict__ rowptr, const int* __restrict__ csr_src,
    const unsigned short* __restrict__ h0bf, const float* __restrict__ as0,
    const float* __restrict__ ad0, const float* __restrict__ b0,
    const float* __restrict__ gamma, const float* __restrict__ beta,
    const float* __restrict__ mean, const float* __restrict__ var,
    float* __restrict__ out, int N) {
  const int lane = threadIdx.x & 63;
  const int wid = threadIdx.x >> 6;
  const int n = blockIdx.x * 4 + wid;
  if (n >= N) return;
  const int h = lane >> 4;
  const int beg = rowptr[n], end = rowptr[n + 1];
  const float adv = ad0[n * 4 + h];
  float4 acc = make_float4(0.f, 0.f, 0.f, 0.f);
  float wsum = 0.f;
  for (int i = beg; i < end; ++i) {
    int s = csr_src[i];
    float x = as0[s * 4 + h] + adv;
    x = x > 0.f ? x : NEG_SLOPE * x;
    float w = __expf(x);
    wsum += w;
    ushort4 v = *reinterpret_cast<const ushort4*>(&h0bf[(size_t)s * 256 + lane * 4]);
    acc.x += w * bf2f(v.x);
    acc.y += w * bf2f(v.y);
    acc.z += w * bf2f(v.z);
    acc.w += w * bf2f(v.w);
  }
  float inv = 1.0f / wsum;
  int j = lane * 4;
  float4 bb = *reinterpret_cast<const float4*>(&b0[j]);
  float4 mu = *reinterpret_cast<const float4*>(&mean[j]);
  float4 gg = *reinterpret_cast<const float4*>(&gamma[j]);
  float4 vv = *reinterpret_cast<const float4*>(&var[j]);
  float4 be = *reinterpret_cast<const float4*>(&beta[j]);
  float4 o;
  o.x = (acc.x * inv + bb.x - mu.x) * (gg.x * rsqrtf(vv.x + BN_EPS)) + be.x;
  o.y = (acc.y * inv + bb.y - mu.y) * (gg.y * rsqrtf(vv.y + BN_EPS)) + be.y;
  o.z = (acc.z * inv + bb.z - mu.z) * (gg.z * rsqrtf(vv.z + BN_EPS)) + be.z;
  o.w = (acc.w * inv + bb.w - mu.w) * (gg.w * rsqrtf(vv.w + BN_EPS)) + be.w;
  o.x = fmaxf(o.x, 0.f); o.y = fmaxf(o.y, 0.f);
  o.z = fmaxf(o.z, 0.f); o.w = fmaxf(o.w, 0.f);
  *reinterpret_cast<float4*>(&out[(size_t)n * 256 + j]) = o;
}

// ------------- layer-1 aggregate: half-wave per node, single pass ----------
__global__ __launch_bounds__(256) void agg1_kernel(
    const int* __restrict__ rowptr, const int* __restrict__ csr_src,
    const float* __restrict__ h1, const float* __restrict__ as1,
    const float* __restrict__ ad1, const float* __restrict__ b1,
    float* __restrict__ out, float* __restrict__ gsum, int N) {
  __shared__ float red[8][32];
  const int t = threadIdx.x;
  const int c = t & 31;
  const int slot = t >> 5;
  const int n = blockIdx.x * 8 + slot;
  float val = 0.f;
  if (n < N) {
    const int beg = rowptr[n], end = rowptr[n + 1];
    const float adv = ad1[n];
    float acc = 0.f, wsum = 0.f;
    for (int i = beg; i < end; ++i) {
      int s = csr_src[i];
      float x = as1[s] + adv;
      x = x > 0.f ? x : NEG_SLOPE * x;
      float w = __expf(x);
      wsum += w;
      acc += w * h1[(size_t)s * 32 + c];
    }
    val = acc / wsum + b1[c];
    out[(size_t)n * 32 + c] = val;
  }
  red[slot][c] = val;
  __syncthreads();
  if (t < 32) {
    float s = 0.f;
    #pragma unroll
    for (int i = 0; i < 8; ++i) s += red[i][t];
    atomicAdd(&gsum[t], s);
  }
}

// ------------- prediction head (1 block, 64 threads) -----------------------
__global__ void pred_kernel(
    const float* __restrict__ gsum, const float* __restrict__ hW1,
    const float* __restrict__ hb1, const float* __restrict__ hW2,
    const float* __restrict__ hb2, float* __restrict__ out, int N) {
  int j = threadIdx.x;
  float invN = 1.0f / (float)N;
  float acc = hb1[j];
  #pragma unroll
  for (int c = 0; c < 32; ++c) acc += (gsum[c] * invN) * hW1[c * 64 + j];
  acc = fmaxf(acc, 0.f);
  float v = acc * hW2[j];
  #pragma unroll
  for (int off = 1; off < 64; off <<= 1) v += __shfl_xor(v, off);
  if (j == 0) out[(size_t)N * 32] = v + hb2[0];
}

// ---------------------------------------------------------------------------
extern "C" void kernel_launch(void* const* d_in, const int* in_sizes, int n_in,
                              void* d_out, int out_size, void* d_ws, size_t ws_size,
                              hipStream_t stream) {
  const float* x       = (const float*)d_in[0];
  const int*   ei      = (const int*)d_in[1];
  const float* W0      = (const float*)d_in[2];
  const float* a_src0  = (const float*)d_in[3];
  const float* a_dst0  = (const float*)d_in[4];
  const float* b0      = (const float*)d_in[5];
  const float* bn_g    = (const float*)d_in[6];
  const float* bn_b    = (const float*)d_in[7];
  const float* bn_m    = (const float*)d_in[8];
  const float* bn_v    = (const float*)d_in[9];
  const float* W1      = (const float*)d_in[10];
  const float* a_src1  = (const float*)d_in[11];
  const float* a_dst1  = (const float*)d_in[12];
  const float* b1      = (const float*)d_in[13];
  const float* hW1     = (const float*)d_in[14];
  const float* hb1     = (const float*)d_in[15];
  const float* hW2     = (const float*)d_in[16];
  const float* hb2     = (const float*)d_in[17];

  const int N = in_sizes[0] / 128;
  const int E = in_sizes[1] / 2;
  const int Etot = E + N;
  const int* srcs = ei;
  const int* dsts = ei + E;
  const int NB = (N + 255) / 256;

  float* out = (float*)d_out;

  // workspace layout (4-byte units)
  float* ws = (float*)d_ws;
  size_t off = 0;
  unsigned short* h0bf = (unsigned short*)(ws + off); off += (size_t)N * 128;  // N*256 bf16
  unsigned short* w0sw = (unsigned short*)(ws + off); off += 16384;            // 32768 bf16
  float* agg0   = ws + off; off += (size_t)N * 256;
  float* h1     = ws + off; off += (size_t)N * 32;
  float* as0    = ws + off; off += (size_t)N * 4;
  float* ad0    = ws + off; off += (size_t)N * 4;
  float* as1    = ws + off; off += (size_t)N;
  float* ad1    = ws + off; off += (size_t)N;
  int* rowptr   = (int*)(ws + off); off += (size_t)N + 1;
  int* cursor   = (int*)(ws + off); off += (size_t)N;
  int* bsum     = (int*)(ws + off); off += 256;
  int* csr_src  = (int*)(ws + off); off += (size_t)Etot;
  // --- zeroed region (contiguous): deg + gsum ---
  size_t zoff = off;
  int* deg      = (int*)(ws + off); off += (size_t)N;
  float* gsum   = ws + off; off += 32;

  hipMemsetAsync(ws + zoff, 0, (off - zoff) * sizeof(float), stream);

  auto cdiv = [](long a, long b) { return (int)((a + b - 1) / b); };

  // CSR build (graph-only)
  hist_kernel<<<cdiv(Etot, 256), 256, 0, stream>>>(dsts, deg, E, N);
  scan_block_kernel<<<NB, 256, 0, stream>>>(deg, rowptr, bsum, N);
  scan_bsum_kernel<<<1, 256, 0, stream>>>(bsum, NB);
  scan_add_kernel<<<NB, 256, 0, stream>>>(rowptr, bsum, cursor, N, Etot);
  scatter_kernel<<<cdiv(Etot, 256), 256, 0, stream>>>(srcs, dsts, cursor, csr_src, E, N);

  // layer 0
  w0_swizzle_kernel<<<128, 256, 0, stream>>>(W0, w0sw);
  gemm0_mfma_kernel<<<cdiv(N, 64), 256, 0, stream>>>(
      x, w0sw, a_src0, a_dst0, h0bf, as0, ad0, N);
  agg0_kernel<<<cdiv(N, 4), 256, 0, stream>>>(rowptr, csr_src, h0bf, as0, ad0,
                                              b0, bn_g, bn_b, bn_m, bn_v, agg0, N);

  // layer 1
  gemm1_kernel<<<cdiv(N, 128), 256, 0, stream>>>(
      agg0, W1, a_src1, a_dst1, h1, as1, ad1, N);
  agg1_kernel<<<cdiv(N, 8), 256, 0, stream>>>(rowptr, csr_src, h1, as1, ad1,
                                              b1, out, gsum, N);

  // head
  pred_kernel<<<1, 64, 0, stream>>>(gsum, hW1, hb1, hW2, hb2, out, N);
}

// Round 5
// 389.218 us; speedup vs baseline: 4.2897x; 1.3179x over previous
//
#include <hip/hip_runtime.h>

// ---------------------------------------------------------------------------
// SupervisedGATEncoder: 2-layer GAT (4 heads x 64 -> BN -> ReLU -> 1 head x 32)
// + graph-mean prediction head.
//
// R5: (a) agg0/agg1 edge loops unrolled x4 (memory-level parallelism for the
// latency-bound gathers); (b) agg0 output stored bf16; (c) gemm1 -> bf16 MFMA
// (A straight from L3-hot global, W1 pre-swizzled), h1 stored bf16 so agg1's
// gather traffic halves. gemm0 MFMA + fused alphas unchanged. CSR unchanged.
// ---------------------------------------------------------------------------

#define NEG_SLOPE 0.2f
#define BN_EPS 1e-5f

typedef __attribute__((ext_vector_type(8))) short bf16x8;
typedef __attribute__((ext_vector_type(4))) float f32x4;

__device__ __forceinline__ float bf2f(unsigned short u) {
  return __uint_as_float((unsigned)u << 16);
}
__device__ __forceinline__ unsigned short f2bf(float f) {
  unsigned u = __float_as_uint(f);
  u += 0x7fff + ((u >> 16) & 1);   // round-to-nearest-even
  return (unsigned short)(u >> 16);
}
__device__ __forceinline__ float lrelu(float x) {
  return x > 0.f ? x : NEG_SLOPE * x;
}

// ------------- W0 + W1 -> bf16, swizzled to MFMA B-fragment order ----------
// w0sw[(((h*4+ci)*4+ks)*64+l)*8+j] = W0[ks*32+(l>>4)*8+j][h*64+ci*16+(l&15)]
// w1sw[(((ci*8)+ks)*64+l)*8+j]     = W1[ks*32+(l>>4)*8+j][ci*16+(l&15)]
__global__ __launch_bounds__(256) void w_swizzle_kernel(
    const float* __restrict__ W0, const float* __restrict__ W1,
    unsigned short* __restrict__ w0sw, unsigned short* __restrict__ w1sw) {
  int o = blockIdx.x * 256 + threadIdx.x;
  if (o < 32768) {
    int j = o & 7, l = (o >> 3) & 63, ks = (o >> 9) & 3,
        ci = (o >> 11) & 3, h = (o >> 13) & 3;
    int row = ks * 32 + (l >> 4) * 8 + j;
    int col = h * 64 + ci * 16 + (l & 15);
    w0sw[o] = f2bf(W0[row * 256 + col]);
  } else if (o < 40960) {
    int o2 = o - 32768;
    int j = o2 & 7, l = (o2 >> 3) & 63, ks = (o2 >> 9) & 7, ci = (o2 >> 12) & 1;
    int row = ks * 32 + (l >> 4) * 8 + j;
    int col = ci * 16 + (l & 15);
    w1sw[o2] = f2bf(W1[row * 32 + col]);
  }
}

// ---------------- GEMM0 (MFMA): h0[M,256] = x[M,128] @ W0[128,256] ---------
__global__ __launch_bounds__(256) void gemm0_mfma_kernel(
    const float* __restrict__ x, const unsigned short* __restrict__ w0sw,
    const float* __restrict__ a_src0, const float* __restrict__ a_dst0,
    unsigned short* __restrict__ h0bf, float* __restrict__ as0,
    float* __restrict__ ad0, int M) {
  __shared__ unsigned short Asw[16 * 64 * 8];   // 16 KB
  const int t = threadIdx.x;
  const int lane = t & 63;
  const int h = t >> 6;            // wave id == head
  const int row0 = blockIdx.x * 64;

  #pragma unroll
  for (int i = 0; i < 8; ++i) {
    int q = t + 256 * i;
    int r = q >> 5, c4 = q & 31;
    int gr = row0 + r;
    float4 v = make_float4(0.f, 0.f, 0.f, 0.f);
    if (gr < M) v = *reinterpret_cast<const float4*>(&x[(size_t)gr * 128 + c4 * 4]);
    int ks = c4 >> 3;
    int lane_hi = (c4 >> 1) & 3;
    int j0 = (c4 & 1) * 4;
    int slot = (r >> 4) * 4 + ks;
    int dlane = (r & 15) + 16 * lane_hi;
    ushort4 o;
    o.x = f2bf(v.x); o.y = f2bf(v.y); o.z = f2bf(v.z); o.w = f2bf(v.w);
    *reinterpret_cast<ushort4*>(&Asw[(slot * 64 + dlane) * 8 + j0]) = o;
  }
  __syncthreads();

  f32x4 acc[4][4] = {};
  const bf16x8* wp = reinterpret_cast<const bf16x8*>(w0sw);
  #pragma unroll
  for (int ks = 0; ks < 4; ++ks) {
    bf16x8 bfrag[4];
    #pragma unroll
    for (int ci = 0; ci < 4; ++ci)
      bfrag[ci] = wp[(h * 16 + ci * 4 + ks) * 64 + lane];
    #pragma unroll
    for (int ri = 0; ri < 4; ++ri) {
      bf16x8 af = *reinterpret_cast<const bf16x8*>(&Asw[((ri * 4 + ks) * 64 + lane) * 8]);
      #pragma unroll
      for (int ci = 0; ci < 4; ++ci)
        acc[ri][ci] = __builtin_amdgcn_mfma_f32_16x16x32_bf16(af, bfrag[ci], acc[ri][ci], 0, 0, 0);
    }
  }

  float av[4], dv[4];
  #pragma unroll
  for (int ci = 0; ci < 4; ++ci) {
    av[ci] = a_src0[h * 64 + ci * 16 + (lane & 15)];
    dv[ci] = a_dst0[h * 64 + ci * 16 + (lane & 15)];
  }
  const int mrow = (lane >> 4) * 4;
  #pragma unroll
  for (int ri = 0; ri < 4; ++ri) {
    #pragma unroll
    for (int r = 0; r < 4; ++r) {
      int gr = row0 + ri * 16 + mrow + r;
      float ps = acc[ri][0][r] * av[0] + acc[ri][1][r] * av[1] +
                 acc[ri][2][r] * av[2] + acc[ri][3][r] * av[3];
      float pd = acc[ri][0][r] * dv[0] + acc[ri][1][r] * dv[1] +
                 acc[ri][2][r] * dv[2] + acc[ri][3][r] * dv[3];
      #pragma unroll
      for (int off = 1; off < 16; off <<= 1) {
        ps += __shfl_xor(ps, off);
        pd += __shfl_xor(pd, off);
      }
      if (gr < M) {
        #pragma unroll
        for (int ci = 0; ci < 4; ++ci)
          h0bf[(size_t)gr * 256 + h * 64 + ci * 16 + (lane & 15)] = f2bf(acc[ri][ci][r]);
        if ((lane & 15) == 0) { as0[gr * 4 + h] = ps; ad0[gr * 4 + h] = pd; }
      }
    }
  }
}

// ------------- GEMM1 (MFMA): h1[M,32] = agg0bf[M,256] @ W1[256,32] ---------
// wave = 16 rows x 32 cols, K=256 (8 MFMA steps x 2 col-frags). A-fragments
// straight from global (agg0bf is L3-hot). + fused alpha1, bf16 h1 out.
__global__ __launch_bounds__(256) void gemm1_mfma_kernel(
    const unsigned short* __restrict__ agg0bf,
    const unsigned short* __restrict__ w1sw,
    const float* __restrict__ a_src1, const float* __restrict__ a_dst1,
    unsigned short* __restrict__ h1bf, float* __restrict__ as1,
    float* __restrict__ ad1, int M) {
  const int t = threadIdx.x;
  const int lane = t & 63;
  const int w = t >> 6;
  const int rbase = blockIdx.x * 64 + w * 16;
  const int arow = rbase + (lane & 15);
  const int ar = arow < M ? arow : M - 1;   // clamp: A row m only affects C row m
  const bf16x8* ap = reinterpret_cast<const bf16x8*>(agg0bf) + (size_t)ar * 32;
  const bf16x8* bp = reinterpret_cast<const bf16x8*>(w1sw);

  f32x4 acc[2] = {};
  #pragma unroll
  for (int ks = 0; ks < 8; ++ks) {
    bf16x8 af = ap[ks * 4 + (lane >> 4)];
    acc[0] = __builtin_amdgcn_mfma_f32_16x16x32_bf16(af, bp[(0 * 8 + ks) * 64 + lane], acc[0], 0, 0, 0);
    acc[1] = __builtin_amdgcn_mfma_f32_16x16x32_bf16(af, bp[(1 * 8 + ks) * 64 + lane], acc[1], 0, 0, 0);
  }

  float av[2], dv[2];
  #pragma unroll
  for (int ci = 0; ci < 2; ++ci) {
    av[ci] = a_src1[ci * 16 + (lane & 15)];
    dv[ci] = a_dst1[ci * 16 + (lane & 15)];
  }
  #pragma unroll
  for (int r = 0; r < 4; ++r) {
    int gr = rbase + (lane >> 4) * 4 + r;
    float ps = acc[0][r] * av[0] + acc[1][r] * av[1];
    float pd = acc[0][r] * dv[0] + acc[1][r] * dv[1];
    #pragma unroll
    for (int off = 1; off < 16; off <<= 1) {
      ps += __shfl_xor(ps, off);
      pd += __shfl_xor(pd, off);
    }
    if (gr < M) {
      h1bf[(size_t)gr * 32 + (lane & 15)]      = f2bf(acc[0][r]);
      h1bf[(size_t)gr * 32 + 16 + (lane & 15)] = f2bf(acc[1][r]);
      if ((lane & 15) == 0) { as1[gr] = ps; ad1[gr] = pd; }
    }
  }
}

// ------------------------- CSR build ---------------------------------------
__global__ __launch_bounds__(256) void hist_kernel(
    const int* __restrict__ dsts, int* __restrict__ deg, int E, int N) {
  int e = blockIdx.x * 256 + threadIdx.x;
  if (e >= E + N) return;
  int d = (e < E) ? dsts[e] : e - E;
  atomicAdd(&deg[d], 1);
}

__global__ __launch_bounds__(256) void scan_block_kernel(
    const int* __restrict__ deg, int* __restrict__ excl,
    int* __restrict__ bsum, int N) {
  __shared__ int tmp[256];
  int i = blockIdx.x * 256 + threadIdx.x;
  int v = (i < N) ? deg[i] : 0;
  tmp[threadIdx.x] = v;
  __syncthreads();
  #pragma unroll
  for (int off = 1; off < 256; off <<= 1) {
    int t = (threadIdx.x >= off) ? tmp[threadIdx.x - off] : 0;
    __syncthreads();
    tmp[threadIdx.x] += t;
    __syncthreads();
  }
  if (i < N) excl[i] = tmp[threadIdx.x] - v;
  if (threadIdx.x == 255) bsum[blockIdx.x] = tmp[255];
}

__global__ __launch_bounds__(256) void scan_bsum_kernel(int* __restrict__ bsum, int NB) {
  __shared__ int tmp[256];
  int i = threadIdx.x;
  int v = (i < NB) ? bsum[i] : 0;
  tmp[i] = v;
  __syncthreads();
  #pragma unroll
  for (int off = 1; off < 256; off <<= 1) {
    int t = (i >= off) ? tmp[i - off] : 0;
    __syncthreads();
    tmp[i] += t;
    __syncthreads();
  }
  if (i < NB) bsum[i] = tmp[i] - v;
}

__global__ __launch_bounds__(256) void scan_add_kernel(
    int* __restrict__ rowptr, const int* __restrict__ bsum,
    int* __restrict__ cursor, int N, int Etot) {
  int i = blockIdx.x * 256 + threadIdx.x;
  if (i < N) {
    int r = rowptr[i] + bsum[blockIdx.x];
    rowptr[i] = r;
    cursor[i] = r;
  }
  if (i == 0) rowptr[N] = Etot;
}

__global__ __launch_bounds__(256) void scatter_kernel(
    const int* __restrict__ srcs, const int* __restrict__ dsts,
    int* __restrict__ cursor, int* __restrict__ csr_src, int E, int N) {
  int e = blockIdx.x * 256 + threadIdx.x;
  if (e >= E + N) return;
  int s, d;
  if (e < E) { s = srcs[e]; d = dsts[e]; } else { s = d = e - E; }
  int pos = atomicAdd(&cursor[d], 1);
  csr_src[pos] = s;
}

// ------------- layer-0 aggregate: one wave per node, unroll x4 -------------
// Single-pass softmax (no max shift). h0 bf16 gather, fp32 accumulate.
// Fused +b0, BN(eval), ReLU; output bf16.
__global__ __launch_bounds__(256) void agg0_kernel(
    const int* __restrict__ rowptr, const int* __restrict__ csr_src,
    const unsigned short* __restrict__ h0bf, const float* __restrict__ as0,
    const float* __restrict__ ad0, const float* __restrict__ b0,
    const float* __restrict__ gamma, const float* __restrict__ beta,
    const float* __restrict__ mean, const float* __restrict__ var,
    unsigned short* __restrict__ outbf, int N) {
  const int lane = threadIdx.x & 63;
  const int wid = threadIdx.x >> 6;
  const int n = blockIdx.x * 4 + wid;
  if (n >= N) return;
  const int h = lane >> 4;
  const int beg = rowptr[n], end = rowptr[n + 1];
  const float adv = ad0[n * 4 + h];
  float4 acc = make_float4(0.f, 0.f, 0.f, 0.f);
  float wsum = 0.f;
  int i = beg;
  for (; i + 4 <= end; i += 4) {
    int s0 = csr_src[i + 0], s1 = csr_src[i + 1],
        s2 = csr_src[i + 2], s3 = csr_src[i + 3];
    float x0 = as0[s0 * 4 + h] + adv, x1 = as0[s1 * 4 + h] + adv,
          x2 = as0[s2 * 4 + h] + adv, x3 = as0[s3 * 4 + h] + adv;
    ushort4 v0 = *reinterpret_cast<const ushort4*>(&h0bf[(size_t)s0 * 256 + lane * 4]);
    ushort4 v1 = *reinterpret_cast<const ushort4*>(&h0bf[(size_t)s1 * 256 + lane * 4]);
    ushort4 v2 = *reinterpret_cast<const ushort4*>(&h0bf[(size_t)s2 * 256 + lane * 4]);
    ushort4 v3 = *reinterpret_cast<const ushort4*>(&h0bf[(size_t)s3 * 256 + lane * 4]);
    float w0 = __expf(lrelu(x0)), w1 = __expf(lrelu(x1)),
          w2 = __expf(lrelu(x2)), w3 = __expf(lrelu(x3));
    wsum += (w0 + w1) + (w2 + w3);
    acc.x += w0 * bf2f(v0.x) + w1 * bf2f(v1.x) + w2 * bf2f(v2.x) + w3 * bf2f(v3.x);
    acc.y += w0 * bf2f(v0.y) + w1 * bf2f(v1.y) + w2 * bf2f(v2.y) + w3 * bf2f(v3.y);
    acc.z += w0 * bf2f(v0.z) + w1 * bf2f(v1.z) + w2 * bf2f(v2.z) + w3 * bf2f(v3.z);
    acc.w += w0 * bf2f(v0.w) + w1 * bf2f(v1.w) + w2 * bf2f(v2.w) + w3 * bf2f(v3.w);
  }
  for (; i < end; ++i) {
    int s = csr_src[i];
    float x = as0[s * 4 + h] + adv;
    float w = __expf(lrelu(x));
    wsum += w;
    ushort4 v = *reinterpret_cast<const ushort4*>(&h0bf[(size_t)s * 256 + lane * 4]);
    acc.x += w * bf2f(v.x); acc.y += w * bf2f(v.y);
    acc.z += w * bf2f(v.z); acc.w += w * bf2f(v.w);
  }
  float inv = 1.0f / wsum;
  int j = lane * 4;
  float4 bb = *reinterpret_cast<const float4*>(&b0[j]);
  float4 mu = *reinterpret_cast<const float4*>(&mean[j]);
  float4 gg = *reinterpret_cast<const float4*>(&gamma[j]);
  float4 vv = *reinterpret_cast<const float4*>(&var[j]);
  float4 be = *reinterpret_cast<const float4*>(&beta[j]);
  float4 o;
  o.x = (acc.x * inv + bb.x - mu.x) * (gg.x * rsqrtf(vv.x + BN_EPS)) + be.x;
  o.y = (acc.y * inv + bb.y - mu.y) * (gg.y * rsqrtf(vv.y + BN_EPS)) + be.y;
  o.z = (acc.z * inv + bb.z - mu.z) * (gg.z * rsqrtf(vv.z + BN_EPS)) + be.z;
  o.w = (acc.w * inv + bb.w - mu.w) * (gg.w * rsqrtf(vv.w + BN_EPS)) + be.w;
  ushort4 ob;
  ob.x = f2bf(fmaxf(o.x, 0.f)); ob.y = f2bf(fmaxf(o.y, 0.f));
  ob.z = f2bf(fmaxf(o.z, 0.f)); ob.w = f2bf(fmaxf(o.w, 0.f));
  *reinterpret_cast<ushort4*>(&outbf[(size_t)n * 256 + j]) = ob;
}

// ------------- layer-1 aggregate: half-wave per node, unroll x4 ------------
__global__ __launch_bounds__(256) void agg1_kernel(
    const int* __restrict__ rowptr, const int* __restrict__ csr_src,
    const unsigned short* __restrict__ h1bf, const float* __restrict__ as1,
    const float* __restrict__ ad1, const float* __restrict__ b1,
    float* __restrict__ out, float* __restrict__ gsum, int N) {
  __shared__ float red[8][32];
  const int t = threadIdx.x;
  const int c = t & 31;
  const int slot = t >> 5;
  const int n = blockIdx.x * 8 + slot;
  float val = 0.f;
  if (n < N) {
    const int beg = rowptr[n], end = rowptr[n + 1];
    const float adv = ad1[n];
    float acc = 0.f, wsum = 0.f;
    int i = beg;
    for (; i + 4 <= end; i += 4) {
      int s0 = csr_src[i + 0], s1 = csr_src[i + 1],
          s2 = csr_src[i + 2], s3 = csr_src[i + 3];
      float x0 = as1[s0] + adv, x1 = as1[s1] + adv,
            x2 = as1[s2] + adv, x3 = as1[s3] + adv;
      unsigned short u0 = h1bf[(size_t)s0 * 32 + c];
      unsigned short u1 = h1bf[(size_t)s1 * 32 + c];
      unsigned short u2 = h1bf[(size_t)s2 * 32 + c];
      unsigned short u3 = h1bf[(size_t)s3 * 32 + c];
      float w0 = __expf(lrelu(x0)), w1 = __expf(lrelu(x1)),
            w2 = __expf(lrelu(x2)), w3 = __expf(lrelu(x3));
      wsum += (w0 + w1) + (w2 + w3);
      acc += w0 * bf2f(u0) + w1 * bf2f(u1) + w2 * bf2f(u2) + w3 * bf2f(u3);
    }
    for (; i < end; ++i) {
      int s = csr_src[i];
      float w = __expf(lrelu(as1[s] + adv));
      wsum += w;
      acc += w * bf2f(h1bf[(size_t)s * 32 + c]);
    }
    val = acc / wsum + b1[c];
    out[(size_t)n * 32 + c] = val;
  }
  red[slot][c] = val;
  __syncthreads();
  if (t < 32) {
    float s = 0.f;
    #pragma unroll
    for (int i = 0; i < 8; ++i) s += red[i][t];
    atomicAdd(&gsum[t], s);
  }
}

// ------------- prediction head (1 block, 64 threads) -----------------------
__global__ void pred_kernel(
    const float* __restrict__ gsum, const float* __restrict__ hW1,
    const float* __restrict__ hb1, const float* __restrict__ hW2,
    const float* __restrict__ hb2, float* __restrict__ out, int N) {
  int j = threadIdx.x;
  float invN = 1.0f / (float)N;
  float acc = hb1[j];
  #pragma unroll
  for (int c = 0; c < 32; ++c) acc += (gsum[c] * invN) * hW1[c * 64 + j];
  acc = fmaxf(acc, 0.f);
  float v = acc * hW2[j];
  #pragma unroll
  for (int off = 1; off < 64; off <<= 1) v += __shfl_xor(v, off);
  if (j == 0) out[(size_t)N * 32] = v + hb2[0];
}

// ---------------------------------------------------------------------------
extern "C" void kernel_launch(void* const* d_in, const int* in_sizes, int n_in,
                              void* d_out, int out_size, void* d_ws, size_t ws_size,
                              hipStream_t stream) {
  const float* x       = (const float*)d_in[0];
  const int*   ei      = (const int*)d_in[1];
  const float* W0      = (const float*)d_in[2];
  const float* a_src0  = (const float*)d_in[3];
  const float* a_dst0  = (const float*)d_in[4];
  const float* b0      = (const float*)d_in[5];
  const float* bn_g    = (const float*)d_in[6];
  const float* bn_b    = (const float*)d_in[7];
  const float* bn_m    = (const float*)d_in[8];
  const float* bn_v    = (const float*)d_in[9];
  const float* W1      = (const float*)d_in[10];
  const float* a_src1  = (const float*)d_in[11];
  const float* a_dst1  = (const float*)d_in[12];
  const float* b1      = (const float*)d_in[13];
  const float* hW1     = (const float*)d_in[14];
  const float* hb1     = (const float*)d_in[15];
  const float* hW2     = (const float*)d_in[16];
  const float* hb2     = (const float*)d_in[17];

  const int N = in_sizes[0] / 128;
  const int E = in_sizes[1] / 2;
  const int Etot = E + N;
  const int* srcs = ei;
  const int* dsts = ei + E;
  const int NB = (N + 255) / 256;

  float* out = (float*)d_out;

  // workspace layout (4-byte units)
  float* ws = (float*)d_ws;
  size_t off = 0;
  unsigned short* h0bf   = (unsigned short*)(ws + off); off += (size_t)N * 128;
  unsigned short* agg0bf = (unsigned short*)(ws + off); off += (size_t)N * 128;
  unsigned short* h1bf   = (unsigned short*)(ws + off); off += (size_t)N * 16;
  unsigned short* w0sw   = (unsigned short*)(ws + off); off += 16384;
  unsigned short* w1sw   = (unsigned short*)(ws + off); off += 4096;
  float* as0    = ws + off; off += (size_t)N * 4;
  float* ad0    = ws + off; off += (size_t)N * 4;
  float* as1    = ws + off; off += (size_t)N;
  float* ad1    = ws + off; off += (size_t)N;
  int* rowptr   = (int*)(ws + off); off += (size_t)N + 1;
  int* cursor   = (int*)(ws + off); off += (size_t)N;
  int* bsum     = (int*)(ws + off); off += 256;
  int* csr_src  = (int*)(ws + off); off += (size_t)Etot;
  // --- zeroed region (contiguous): deg + gsum ---
  size_t zoff = off;
  int* deg      = (int*)(ws + off); off += (size_t)N;
  float* gsum   = ws + off; off += 32;

  hipMemsetAsync(ws + zoff, 0, (off - zoff) * sizeof(float), stream);

  auto cdiv = [](long a, long b) { return (int)((a + b - 1) / b); };

  // CSR build (graph-only)
  hist_kernel<<<cdiv(Etot, 256), 256, 0, stream>>>(dsts, deg, E, N);
  scan_block_kernel<<<NB, 256, 0, stream>>>(deg, rowptr, bsum, N);
  scan_bsum_kernel<<<1, 256, 0, stream>>>(bsum, NB);
  scan_add_kernel<<<NB, 256, 0, stream>>>(rowptr, bsum, cursor, N, Etot);
  scatter_kernel<<<cdiv(Etot, 256), 256, 0, stream>>>(srcs, dsts, cursor, csr_src, E, N);

  // weight swizzles (W0 + W1)
  w_swizzle_kernel<<<160, 256, 0, stream>>>(W0, W1, w0sw, w1sw);

  // layer 0
  gemm0_mfma_kernel<<<cdiv(N, 64), 256, 0, stream>>>(
      x, w0sw, a_src0, a_dst0, h0bf, as0, ad0, N);
  agg0_kernel<<<cdiv(N, 4), 256, 0, stream>>>(rowptr, csr_src, h0bf, as0, ad0,
                                              b0, bn_g, bn_b, bn_m, bn_v, agg0bf, N);

  // layer 1
  gemm1_mfma_kernel<<<cdiv(N, 64), 256, 0, stream>>>(
      agg0bf, w1sw, a_src1, a_dst1, h1bf, as1, ad1, N);
  agg1_kernel<<<cdiv(N, 8), 256, 0, stream>>>(rowptr, csr_src, h1bf, as1, ad1,
                                              b1, out, gsum, N);

  // head
  pred_kernel<<<1, 64, 0, stream>>>(gsum, hW1, hb1, hW2, hb2, out, N);
}

// Round 6
// 342.426 us; speedup vs baseline: 4.8758x; 1.1366x over previous
//
#include <hip/hip_runtime.h>

// ---------------------------------------------------------------------------
// SupervisedGATEncoder: 2-layer GAT (4 heads x 64 -> BN -> ReLU -> 1 head x 32)
// + graph-mean prediction head.
//
// R6: (a) agg1 no longer atomically accumulates the graph sum (6250-deep
// same-address atomic chain removed); a separate 128-block reduce computes
// gsum from `out`. (b) agg1 restructured: one wave per node, 2 edges in
// parallel (lane halves), unroll x4 -> 8 edge-rows in flight. Rest as R5.
// ---------------------------------------------------------------------------

#define NEG_SLOPE 0.2f
#define BN_EPS 1e-5f

typedef __attribute__((ext_vector_type(8))) short bf16x8;
typedef __attribute__((ext_vector_type(4))) float f32x4;

__device__ __forceinline__ float bf2f(unsigned short u) {
  return __uint_as_float((unsigned)u << 16);
}
__device__ __forceinline__ unsigned short f2bf(float f) {
  unsigned u = __float_as_uint(f);
  u += 0x7fff + ((u >> 16) & 1);   // round-to-nearest-even
  return (unsigned short)(u >> 16);
}
__device__ __forceinline__ float lrelu(float x) {
  return x > 0.f ? x : NEG_SLOPE * x;
}

// ------------- W0 + W1 -> bf16, swizzled to MFMA B-fragment order ----------
__global__ __launch_bounds__(256) void w_swizzle_kernel(
    const float* __restrict__ W0, const float* __restrict__ W1,
    unsigned short* __restrict__ w0sw, unsigned short* __restrict__ w1sw) {
  int o = blockIdx.x * 256 + threadIdx.x;
  if (o < 32768) {
    int j = o & 7, l = (o >> 3) & 63, ks = (o >> 9) & 3,
        ci = (o >> 11) & 3, h = (o >> 13) & 3;
    int row = ks * 32 + (l >> 4) * 8 + j;
    int col = h * 64 + ci * 16 + (l & 15);
    w0sw[o] = f2bf(W0[row * 256 + col]);
  } else if (o < 40960) {
    int o2 = o - 32768;
    int j = o2 & 7, l = (o2 >> 3) & 63, ks = (o2 >> 9) & 7, ci = (o2 >> 12) & 1;
    int row = ks * 32 + (l >> 4) * 8 + j;
    int col = ci * 16 + (l & 15);
    w1sw[o2] = f2bf(W1[row * 32 + col]);
  }
}

// ---------------- GEMM0 (MFMA): h0[M,256] = x[M,128] @ W0[128,256] ---------
__global__ __launch_bounds__(256) void gemm0_mfma_kernel(
    const float* __restrict__ x, const unsigned short* __restrict__ w0sw,
    const float* __restrict__ a_src0, const float* __restrict__ a_dst0,
    unsigned short* __restrict__ h0bf, float* __restrict__ as0,
    float* __restrict__ ad0, int M) {
  __shared__ unsigned short Asw[16 * 64 * 8];   // 16 KB
  const int t = threadIdx.x;
  const int lane = t & 63;
  const int h = t >> 6;            // wave id == head
  const int row0 = blockIdx.x * 64;

  #pragma unroll
  for (int i = 0; i < 8; ++i) {
    int q = t + 256 * i;
    int r = q >> 5, c4 = q & 31;
    int gr = row0 + r;
    float4 v = make_float4(0.f, 0.f, 0.f, 0.f);
    if (gr < M) v = *reinterpret_cast<const float4*>(&x[(size_t)gr * 128 + c4 * 4]);
    int ks = c4 >> 3;
    int lane_hi = (c4 >> 1) & 3;
    int j0 = (c4 & 1) * 4;
    int slot = (r >> 4) * 4 + ks;
    int dlane = (r & 15) + 16 * lane_hi;
    ushort4 o;
    o.x = f2bf(v.x); o.y = f2bf(v.y); o.z = f2bf(v.z); o.w = f2bf(v.w);
    *reinterpret_cast<ushort4*>(&Asw[(slot * 64 + dlane) * 8 + j0]) = o;
  }
  __syncthreads();

  f32x4 acc[4][4] = {};
  const bf16x8* wp = reinterpret_cast<const bf16x8*>(w0sw);
  #pragma unroll
  for (int ks = 0; ks < 4; ++ks) {
    bf16x8 bfrag[4];
    #pragma unroll
    for (int ci = 0; ci < 4; ++ci)
      bfrag[ci] = wp[(h * 16 + ci * 4 + ks) * 64 + lane];
    #pragma unroll
    for (int ri = 0; ri < 4; ++ri) {
      bf16x8 af = *reinterpret_cast<const bf16x8*>(&Asw[((ri * 4 + ks) * 64 + lane) * 8]);
      #pragma unroll
      for (int ci = 0; ci < 4; ++ci)
        acc[ri][ci] = __builtin_amdgcn_mfma_f32_16x16x32_bf16(af, bfrag[ci], acc[ri][ci], 0, 0, 0);
    }
  }

  float av[4], dv[4];
  #pragma unroll
  for (int ci = 0; ci < 4; ++ci) {
    av[ci] = a_src0[h * 64 + ci * 16 + (lane & 15)];
    dv[ci] = a_dst0[h * 64 + ci * 16 + (lane & 15)];
  }
  const int mrow = (lane >> 4) * 4;
  #pragma unroll
  for (int ri = 0; ri < 4; ++ri) {
    #pragma unroll
    for (int r = 0; r < 4; ++r) {
      int gr = row0 + ri * 16 + mrow + r;
      float ps = acc[ri][0][r] * av[0] + acc[ri][1][r] * av[1] +
                 acc[ri][2][r] * av[2] + acc[ri][3][r] * av[3];
      float pd = acc[ri][0][r] * dv[0] + acc[ri][1][r] * dv[1] +
                 acc[ri][2][r] * dv[2] + acc[ri][3][r] * dv[3];
      #pragma unroll
      for (int off = 1; off < 16; off <<= 1) {
        ps += __shfl_xor(ps, off);
        pd += __shfl_xor(pd, off);
      }
      if (gr < M) {
        #pragma unroll
        for (int ci = 0; ci < 4; ++ci)
          h0bf[(size_t)gr * 256 + h * 64 + ci * 16 + (lane & 15)] = f2bf(acc[ri][ci][r]);
        if ((lane & 15) == 0) { as0[gr * 4 + h] = ps; ad0[gr * 4 + h] = pd; }
      }
    }
  }
}

// ------------- GEMM1 (MFMA): h1[M,32] = agg0bf[M,256] @ W1[256,32] ---------
__global__ __launch_bounds__(256) void gemm1_mfma_kernel(
    const unsigned short* __restrict__ agg0bf,
    const unsigned short* __restrict__ w1sw,
    const float* __restrict__ a_src1, const float* __restrict__ a_dst1,
    unsigned short* __restrict__ h1bf, float* __restrict__ as1,
    float* __restrict__ ad1, int M) {
  const int t = threadIdx.x;
  const int lane = t & 63;
  const int w = t >> 6;
  const int rbase = blockIdx.x * 64 + w * 16;
  const int arow = rbase + (lane & 15);
  const int ar = arow < M ? arow : M - 1;   // clamp: A row m only affects C row m
  const bf16x8* ap = reinterpret_cast<const bf16x8*>(agg0bf) + (size_t)ar * 32;
  const bf16x8* bp = reinterpret_cast<const bf16x8*>(w1sw);

  f32x4 acc[2] = {};
  #pragma unroll
  for (int ks = 0; ks < 8; ++ks) {
    bf16x8 af = ap[ks * 4 + (lane >> 4)];
    acc[0] = __builtin_amdgcn_mfma_f32_16x16x32_bf16(af, bp[(0 * 8 + ks) * 64 + lane], acc[0], 0, 0, 0);
    acc[1] = __builtin_amdgcn_mfma_f32_16x16x32_bf16(af, bp[(1 * 8 + ks) * 64 + lane], acc[1], 0, 0, 0);
  }

  float av[2], dv[2];
  #pragma unroll
  for (int ci = 0; ci < 2; ++ci) {
    av[ci] = a_src1[ci * 16 + (lane & 15)];
    dv[ci] = a_dst1[ci * 16 + (lane & 15)];
  }
  #pragma unroll
  for (int r = 0; r < 4; ++r) {
    int gr = rbase + (lane >> 4) * 4 + r;
    float ps = acc[0][r] * av[0] + acc[1][r] * av[1];
    float pd = acc[0][r] * dv[0] + acc[1][r] * dv[1];
    #pragma unroll
    for (int off = 1; off < 16; off <<= 1) {
      ps += __shfl_xor(ps, off);
      pd += __shfl_xor(pd, off);
    }
    if (gr < M) {
      h1bf[(size_t)gr * 32 + (lane & 15)]      = f2bf(acc[0][r]);
      h1bf[(size_t)gr * 32 + 16 + (lane & 15)] = f2bf(acc[1][r]);
      if ((lane & 15) == 0) { as1[gr] = ps; ad1[gr] = pd; }
    }
  }
}

// ------------------------- CSR build ---------------------------------------
__global__ __launch_bounds__(256) void hist_kernel(
    const int* __restrict__ dsts, int* __restrict__ deg, int E, int N) {
  int e = blockIdx.x * 256 + threadIdx.x;
  if (e >= E + N) return;
  int d = (e < E) ? dsts[e] : e - E;
  atomicAdd(&deg[d], 1);
}

__global__ __launch_bounds__(256) void scan_block_kernel(
    const int* __restrict__ deg, int* __restrict__ excl,
    int* __restrict__ bsum, int N) {
  __shared__ int tmp[256];
  int i = blockIdx.x * 256 + threadIdx.x;
  int v = (i < N) ? deg[i] : 0;
  tmp[threadIdx.x] = v;
  __syncthreads();
  #pragma unroll
  for (int off = 1; off < 256; off <<= 1) {
    int t = (threadIdx.x >= off) ? tmp[threadIdx.x - off] : 0;
    __syncthreads();
    tmp[threadIdx.x] += t;
    __syncthreads();
  }
  if (i < N) excl[i] = tmp[threadIdx.x] - v;
  if (threadIdx.x == 255) bsum[blockIdx.x] = tmp[255];
}

__global__ __launch_bounds__(256) void scan_bsum_kernel(int* __restrict__ bsum, int NB) {
  __shared__ int tmp[256];
  int i = threadIdx.x;
  int v = (i < NB) ? bsum[i] : 0;
  tmp[i] = v;
  __syncthreads();
  #pragma unroll
  for (int off = 1; off < 256; off <<= 1) {
    int t = (i >= off) ? tmp[i - off] : 0;
    __syncthreads();
    tmp[i] += t;
    __syncthreads();
  }
  if (i < NB) bsum[i] = tmp[i] - v;
}

__global__ __launch_bounds__(256) void scan_add_kernel(
    int* __restrict__ rowptr, const int* __restrict__ bsum,
    int* __restrict__ cursor, int N, int Etot) {
  int i = blockIdx.x * 256 + threadIdx.x;
  if (i < N) {
    int r = rowptr[i] + bsum[blockIdx.x];
    rowptr[i] = r;
    cursor[i] = r;
  }
  if (i == 0) rowptr[N] = Etot;
}

__global__ __launch_bounds__(256) void scatter_kernel(
    const int* __restrict__ srcs, const int* __restrict__ dsts,
    int* __restrict__ cursor, int* __restrict__ csr_src, int E, int N) {
  int e = blockIdx.x * 256 + threadIdx.x;
  if (e >= E + N) return;
  int s, d;
  if (e < E) { s = srcs[e]; d = dsts[e]; } else { s = d = e - E; }
  int pos = atomicAdd(&cursor[d], 1);
  csr_src[pos] = s;
}

// ------------- layer-0 aggregate: one wave per node, unroll x4 -------------
__global__ __launch_bounds__(256) void agg0_kernel(
    const int* __restrict__ rowptr, const int* __restrict__ csr_src,
    const unsigned short* __restrict__ h0bf, const float* __restrict__ as0,
    const float* __restrict__ ad0, const float* __restrict__ b0,
    const float* __restrict__ gamma, const float* __restrict__ beta,
    const float* __restrict__ mean, const float* __restrict__ var,
    unsigned short* __restrict__ outbf, int N) {
  const int lane = threadIdx.x & 63;
  const int wid = threadIdx.x >> 6;
  const int n = blockIdx.x * 4 + wid;
  if (n >= N) return;
  const int h = lane >> 4;
  const int beg = rowptr[n], end = rowptr[n + 1];
  const float adv = ad0[n * 4 + h];
  float4 acc = make_float4(0.f, 0.f, 0.f, 0.f);
  float wsum = 0.f;
  int i = beg;
  for (; i + 4 <= end; i += 4) {
    int s0 = csr_src[i + 0], s1 = csr_src[i + 1],
        s2 = csr_src[i + 2], s3 = csr_src[i + 3];
    float x0 = as0[s0 * 4 + h] + adv, x1 = as0[s1 * 4 + h] + adv,
          x2 = as0[s2 * 4 + h] + adv, x3 = as0[s3 * 4 + h] + adv;
    ushort4 v0 = *reinterpret_cast<const ushort4*>(&h0bf[(size_t)s0 * 256 + lane * 4]);
    ushort4 v1 = *reinterpret_cast<const ushort4*>(&h0bf[(size_t)s1 * 256 + lane * 4]);
    ushort4 v2 = *reinterpret_cast<const ushort4*>(&h0bf[(size_t)s2 * 256 + lane * 4]);
    ushort4 v3 = *reinterpret_cast<const ushort4*>(&h0bf[(size_t)s3 * 256 + lane * 4]);
    float w0 = __expf(lrelu(x0)), w1 = __expf(lrelu(x1)),
          w2 = __expf(lrelu(x2)), w3 = __expf(lrelu(x3));
    wsum += (w0 + w1) + (w2 + w3);
    acc.x += w0 * bf2f(v0.x) + w1 * bf2f(v1.x) + w2 * bf2f(v2.x) + w3 * bf2f(v3.x);
    acc.y += w0 * bf2f(v0.y) + w1 * bf2f(v1.y) + w2 * bf2f(v2.y) + w3 * bf2f(v3.y);
    acc.z += w0 * bf2f(v0.z) + w1 * bf2f(v1.z) + w2 * bf2f(v2.z) + w3 * bf2f(v3.z);
    acc.w += w0 * bf2f(v0.w) + w1 * bf2f(v1.w) + w2 * bf2f(v2.w) + w3 * bf2f(v3.w);
  }
  for (; i < end; ++i) {
    int s = csr_src[i];
    float x = as0[s * 4 + h] + adv;
    float w = __expf(lrelu(x));
    wsum += w;
    ushort4 v = *reinterpret_cast<const ushort4*>(&h0bf[(size_t)s * 256 + lane * 4]);
    acc.x += w * bf2f(v.x); acc.y += w * bf2f(v.y);
    acc.z += w * bf2f(v.z); acc.w += w * bf2f(v.w);
  }
  float inv = 1.0f / wsum;
  int j = lane * 4;
  float4 bb = *reinterpret_cast<const float4*>(&b0[j]);
  float4 mu = *reinterpret_cast<const float4*>(&mean[j]);
  float4 gg = *reinterpret_cast<const float4*>(&gamma[j]);
  float4 vv = *reinterpret_cast<const float4*>(&var[j]);
  float4 be = *reinterpret_cast<const float4*>(&beta[j]);
  float4 o;
  o.x = (acc.x * inv + bb.x - mu.x) * (gg.x * rsqrtf(vv.x + BN_EPS)) + be.x;
  o.y = (acc.y * inv + bb.y - mu.y) * (gg.y * rsqrtf(vv.y + BN_EPS)) + be.y;
  o.z = (acc.z * inv + bb.z - mu.z) * (gg.z * rsqrtf(vv.z + BN_EPS)) + be.z;
  o.w = (acc.w * inv + bb.w - mu.w) * (gg.w * rsqrtf(vv.w + BN_EPS)) + be.w;
  ushort4 ob;
  ob.x = f2bf(fmaxf(o.x, 0.f)); ob.y = f2bf(fmaxf(o.y, 0.f));
  ob.z = f2bf(fmaxf(o.z, 0.f)); ob.w = f2bf(fmaxf(o.w, 0.f));
  *reinterpret_cast<ushort4*>(&outbf[(size_t)n * 256 + j]) = ob;
}

// ------------- layer-1 aggregate: one wave per node, 2 edges parallel ------
// lanes 0-31: even edges, lanes 32-63: odd edges; col = lane&31. Unroll x4
// -> 8 edge-rows in flight. Halves merged via shfl_xor(32). No atomics.
__global__ __launch_bounds__(256) void agg1_kernel(
    const int* __restrict__ rowptr, const int* __restrict__ csr_src,
    const unsigned short* __restrict__ h1bf, const float* __restrict__ as1,
    const float* __restrict__ ad1, const float* __restrict__ b1,
    float* __restrict__ out, int N) {
  const int t = threadIdx.x;
  const int lane = t & 63;
  const int w = t >> 6;
  const int n = blockIdx.x * 4 + w;
  if (n >= N) return;
  const int c = lane & 31;
  const int half = lane >> 5;
  const int beg = rowptr[n], end = rowptr[n + 1];
  const float adv = ad1[n];
  float acc = 0.f, wsum = 0.f;
  int i = beg + half;
  for (; i + 6 < end; i += 8) {
    int s0 = csr_src[i + 0], s1 = csr_src[i + 2],
        s2 = csr_src[i + 4], s3 = csr_src[i + 6];
    float x0 = as1[s0] + adv, x1 = as1[s1] + adv,
          x2 = as1[s2] + adv, x3 = as1[s3] + adv;
    unsigned short u0 = h1bf[(size_t)s0 * 32 + c];
    unsigned short u1 = h1bf[(size_t)s1 * 32 + c];
    unsigned short u2 = h1bf[(size_t)s2 * 32 + c];
    unsigned short u3 = h1bf[(size_t)s3 * 32 + c];
    float w0 = __expf(lrelu(x0)), w1 = __expf(lrelu(x1)),
          w2 = __expf(lrelu(x2)), w3 = __expf(lrelu(x3));
    wsum += (w0 + w1) + (w2 + w3);
    acc += w0 * bf2f(u0) + w1 * bf2f(u1) + w2 * bf2f(u2) + w3 * bf2f(u3);
  }
  for (; i < end; i += 2) {
    int s = csr_src[i];
    float wgt = __expf(lrelu(as1[s] + adv));
    wsum += wgt;
    acc += wgt * bf2f(h1bf[(size_t)s * 32 + c]);
  }
  acc += __shfl_xor(acc, 32);
  wsum += __shfl_xor(wsum, 32);
  if (half == 0) out[(size_t)n * 32 + c] = acc / wsum + b1[c];
}

// ------------- graph-sum reduce over out[N,32] -----------------------------
__global__ __launch_bounds__(256) void gsum_kernel(
    const float* __restrict__ out, float* __restrict__ gsum, int N) {
  __shared__ float red[8][32];
  const int t = threadIdx.x;
  const int c = t & 31;          // stride is a multiple of 32 -> col fixed
  float s = 0.f;
  const size_t total = (size_t)N * 32;
  for (size_t j = (size_t)blockIdx.x * 256 + t; j < total;
       j += (size_t)gridDim.x * 256)
    s += out[j];
  red[t >> 5][c] = s;
  __syncthreads();
  if (t < 32) {
    float v = 0.f;
    #pragma unroll
    for (int i = 0; i < 8; ++i) v += red[i][t];
    atomicAdd(&gsum[t], v);
  }
}

// ------------- prediction head (1 block, 64 threads) -----------------------
__global__ void pred_kernel(
    const float* __restrict__ gsum, const float* __restrict__ hW1,
    const float* __restrict__ hb1, const float* __restrict__ hW2,
    const float* __restrict__ hb2, float* __restrict__ out, int N) {
  int j = threadIdx.x;
  float invN = 1.0f / (float)N;
  float acc = hb1[j];
  #pragma unroll
  for (int c = 0; c < 32; ++c) acc += (gsum[c] * invN) * hW1[c * 64 + j];
  acc = fmaxf(acc, 0.f);
  float v = acc * hW2[j];
  #pragma unroll
  for (int off = 1; off < 64; off <<= 1) v += __shfl_xor(v, off);
  if (j == 0) out[(size_t)N * 32] = v + hb2[0];
}

// ---------------------------------------------------------------------------
extern "C" void kernel_launch(void* const* d_in, const int* in_sizes, int n_in,
                              void* d_out, int out_size, void* d_ws, size_t ws_size,
                              hipStream_t stream) {
  const float* x       = (const float*)d_in[0];
  const int*   ei      = (const int*)d_in[1];
  const float* W0      = (const float*)d_in[2];
  const float* a_src0  = (const float*)d_in[3];
  const float* a_dst0  = (const float*)d_in[4];
  const float* b0      = (const float*)d_in[5];
  const float* bn_g    = (const float*)d_in[6];
  const float* bn_b    = (const float*)d_in[7];
  const float* bn_m    = (const float*)d_in[8];
  const float* bn_v    = (const float*)d_in[9];
  const float* W1      = (const float*)d_in[10];
  const float* a_src1  = (const float*)d_in[11];
  const float* a_dst1  = (const float*)d_in[12];
  const float* b1      = (const float*)d_in[13];
  const float* hW1     = (const float*)d_in[14];
  const float* hb1     = (const float*)d_in[15];
  const float* hW2     = (const float*)d_in[16];
  const float* hb2     = (const float*)d_in[17];

  const int N = in_sizes[0] / 128;
  const int E = in_sizes[1] / 2;
  const int Etot = E + N;
  const int* srcs = ei;
  const int* dsts = ei + E;
  const int NB = (N + 255) / 256;

  float* out = (float*)d_out;

  // workspace layout (4-byte units)
  float* ws = (float*)d_ws;
  size_t off = 0;
  unsigned short* h0bf   = (unsigned short*)(ws + off); off += (size_t)N * 128;
  unsigned short* agg0bf = (unsigned short*)(ws + off); off += (size_t)N * 128;
  unsigned short* h1bf   = (unsigned short*)(ws + off); off += (size_t)N * 16;
  unsigned short* w0sw   = (unsigned short*)(ws + off); off += 16384;
  unsigned short* w1sw   = (unsigned short*)(ws + off); off += 4096;
  float* as0    = ws + off; off += (size_t)N * 4;
  float* ad0    = ws + off; off += (size_t)N * 4;
  float* as1    = ws + off; off += (size_t)N;
  float* ad1    = ws + off; off += (size_t)N;
  int* rowptr   = (int*)(ws + off); off += (size_t)N + 1;
  int* cursor   = (int*)(ws + off); off += (size_t)N;
  int* bsum     = (int*)(ws + off); off += 256;
  int* csr_src  = (int*)(ws + off); off += (size_t)Etot;
  // --- zeroed region (contiguous): deg + gsum ---
  size_t zoff = off;
  int* deg      = (int*)(ws + off); off += (size_t)N;
  float* gsum   = ws + off; off += 32;

  hipMemsetAsync(ws + zoff, 0, (off - zoff) * sizeof(float), stream);

  auto cdiv = [](long a, long b) { return (int)((a + b - 1) / b); };

  // CSR build (graph-only)
  hist_kernel<<<cdiv(Etot, 256), 256, 0, stream>>>(dsts, deg, E, N);
  scan_block_kernel<<<NB, 256, 0, stream>>>(deg, rowptr, bsum, N);
  scan_bsum_kernel<<<1, 256, 0, stream>>>(bsum, NB);
  scan_add_kernel<<<NB, 256, 0, stream>>>(rowptr, bsum, cursor, N, Etot);
  scatter_kernel<<<cdiv(Etot, 256), 256, 0, stream>>>(srcs, dsts, cursor, csr_src, E, N);

  // weight swizzles (W0 + W1)
  w_swizzle_kernel<<<160, 256, 0, stream>>>(W0, W1, w0sw, w1sw);

  // layer 0
  gemm0_mfma_kernel<<<cdiv(N, 64), 256, 0, stream>>>(
      x, w0sw, a_src0, a_dst0, h0bf, as0, ad0, N);
  agg0_kernel<<<cdiv(N, 4), 256, 0, stream>>>(rowptr, csr_src, h0bf, as0, ad0,
                                              b0, bn_g, bn_b, bn_m, bn_v, agg0bf, N);

  // layer 1
  gemm1_mfma_kernel<<<cdiv(N, 64), 256, 0, stream>>>(
      agg0bf, w1sw, a_src1, a_dst1, h1bf, as1, ad1, N);
  agg1_kernel<<<cdiv(N, 4), 256, 0, stream>>>(rowptr, csr_src, h1bf, as1, ad1,
                                              b1, out, N);

  // graph mean + head
  gsum_kernel<<<128, 256, 0, stream>>>(out, gsum, N);
  pred_kernel<<<1, 64, 0, stream>>>(gsum, hW1, hb1, hW2, hb2, out, N);
}